// Round 13
// baseline (294.686 us; speedup 1.0000x reference)
//
#include <hip/hip_runtime.h>
#include <cstdint>
#include <cstddef>

#define PI_F 3.14159265358979323846f

constexpr int BB = 4, NN = 512, BN = 2048, NBIN = 48;

typedef __attribute__((ext_vector_type(8))) short v8s;   // 8 bf16 (4 VGPRs)
typedef __attribute__((ext_vector_type(4))) float v4f;   // MFMA acc

__device__ __forceinline__ unsigned short f2bf(float f) {
  unsigned u = __float_as_uint(f);
  unsigned r = (u + 0x7FFFu + ((u >> 16) & 1u)) >> 16;   // RNE
  return (unsigned short)r;
}
__device__ __forceinline__ float bf2f(unsigned short s) {
  return __uint_as_float(((unsigned)s) << 16);
}

// ---------------------------------------------------------------- steer variants
__device__ __forceinline__ void steer_f32(const float* __restrict__ W, float* __restrict__ K2,
                                          int O, int I, int Ipad, int idx, int total) {
  if (idx >= total) return;
  int i = idx % Ipad;
  int o = (idx / Ipad) % O;
  int k = idx / (Ipad * O);
  int CTc = O * 2;
  size_t r0 = (size_t)((k*Ipad + i)*2 + 0) * CTc + o*2;
  size_t r1 = r0 + CTc;
  if (i >= I) { K2[r0]=0.f; K2[r0+1]=0.f; K2[r1]=0.f; K2[r1+1]=0.f; return; }
  int tt = k % 16;
  float ang = (tt + 0.5f) * (2.0f * PI_F / 16.0f) - PI_F;
  float ct = cosf(ang), st = sinf(ang);
  const float* Wp = W + ((size_t)(k*O + o)*I + i) * 4;
  float w00 = Wp[0], w01 = Wp[1], w10 = Wp[2], w11 = Wp[3];
  float rw00 = ct*w00 - st*w10, rw01 = ct*w01 - st*w11;
  float rw10 = st*w00 + ct*w10, rw11 = st*w01 + ct*w11;
  K2[r0 + 0] = rw00*ct - rw01*st;
  K2[r0 + 1] = rw10*ct - rw11*st;
  K2[r1 + 0] = rw00*st + rw01*ct;
  K2[r1 + 1] = rw10*st + rw11*ct;
}

__device__ __forceinline__ void steer_bf16T(const float* __restrict__ W,
                                            unsigned short* __restrict__ K2T,
                                            int O, int I, int Ipad, int Kd,
                                            int idx, int total) {
  if (idx >= total) return;
  int i = idx % Ipad;
  int o = (idx / Ipad) % O;
  int k = idx / (Ipad * O);
  size_t c0 = (size_t)(o*2 + 0) * Kd + (k*Ipad + i)*2;
  size_t c1 = (size_t)(o*2 + 1) * Kd + (k*Ipad + i)*2;
  if (i >= I) { K2T[c0]=0; K2T[c0+1]=0; K2T[c1]=0; K2T[c1+1]=0; return; }
  int tt = k % 16;
  float ang = (tt + 0.5f) * (2.0f * PI_F / 16.0f) - PI_F;
  float ct = cosf(ang), st = sinf(ang);
  const float* Wp = W + ((size_t)(k*O + o)*I + i) * 4;
  float w00 = Wp[0], w01 = Wp[1], w10 = Wp[2], w11 = Wp[3];
  float rw00 = ct*w00 - st*w10, rw01 = ct*w01 - st*w11;
  float rw10 = st*w00 + ct*w10, rw11 = st*w01 + ct*w11;
  K2T[c0 + 0] = f2bf(rw00*ct - rw01*st);
  K2T[c0 + 1] = f2bf(rw00*st + rw01*ct);
  K2T[c1 + 0] = f2bf(rw10*ct - rw11*st);
  K2T[c1 + 1] = f2bf(rw10*st + rw11*ct);
}

// ---------------------------------------------------------------- setup body (prep + all steers)
__device__ __forceinline__ void setup_body(int blk, int t,
    const float* __restrict__ p0, const float* __restrict__ v0,
    const float* __restrict__ a, const float* __restrict__ other,
    const float* __restrict__ v0enc, float* __restrict__ p1, float* __restrict__ F0,
    const float* Wcf, unsigned short* K2CF, const float* Wco, float* K2CO,
    const float* Wc1, unsigned short* K2C1, const float* Wc2, unsigned short* K2C2,
    const float* Wc3, unsigned short* K2C3, const float* Wc4, float* K2C4) {
  if (blk < 8) {
    int n = blk * 256 + t;
    float p0x = p0[n*2], p0y = p0[n*2+1];
    float v0x = v0[n*2], v0y = v0[n*2+1];
    float ax = a[n*2],  ay = a[n*2+1];
    float v1x = v0x + 0.1f*ax, v1y = v0y + 0.1f*ay;
    p1[n*2]   = p0x + 0.1f*(v0x+v1x)*0.5f;
    p1[n*2+1] = p0y + 0.1f*(v0y+v1y)*0.5f;
    float* F = F0 + (size_t)n*48;
    F[0] = v1x; F[1] = v1y;
    for (int c = 0; c < 3; ++c) {
      F[2+c*2]   = other[(n*3+c)*2];
      F[2+c*2+1] = other[(n*3+c)*2+1];
    }
    for (int c = 0; c < 16; ++c) {
      F[8+c*2]   = v0enc[(n*16+c)*2];
      F[8+c*2+1] = v0enc[(n*16+c)*2+1];
    }
    for (int c = 40; c < 48; ++c) F[c] = 0.0f;
  } else if (blk < 80)  steer_bf16T(Wcf, K2CF, 16, 20, 24, 2304, (blk-8)*256 + t, 18432);
  else if (blk < 83)  steer_f32(Wco, K2CO, 16, 1, 1,   (blk-80)*256 + t, 768);
  else if (blk < 371) steer_bf16T(Wc1, K2C1, 32, 48, 48, 4608, (blk-83)*256 + t, 73728);
  else if (blk < 563) steer_bf16T(Wc2, K2C2, 32, 32, 32, 3072, (blk-371)*256 + t, 49152);
  else if (blk < 755) steer_bf16T(Wc3, K2C3, 32, 32, 32, 3072, (blk-563)*256 + t, 49152);
  else                steer_f32(Wc4, K2C4, 1, 32, 32,  (blk-755)*256 + t, 1536);
}

// ---------------------------------------------------------------- merged setup + pairs (pairs recomputes p1 bit-identically)
__global__ __launch_bounds__(256) void setup_pairs(
    const float* __restrict__ p0, const float* __restrict__ v0,
    const float* __restrict__ a, const float* __restrict__ other,
    const float* __restrict__ v0enc, float* __restrict__ P1, float* __restrict__ F0,
    const float* Wcf, unsigned short* K2CF, const float* Wco, float* K2CO,
    const float* Wc1, unsigned short* K2C1, const float* Wc2, unsigned short* K2C2,
    const float* Wc3, unsigned short* K2C3, const float* Wc4, float* K2C4,
    const float* __restrict__ maskF,
    float* __restrict__ wlF, int* __restrict__ plF, int* __restrict__ cntF,
    const float* __restrict__ box, const float* __restrict__ maskO,
    float* __restrict__ wlO, int* __restrict__ plO, int* __restrict__ cntO) {
  const int t = threadIdx.x;
  if (blockIdx.x < 761) {
    setup_body(blockIdx.x, t, p0, v0, a, other, v0enc, P1, F0,
               Wcf, K2CF, Wco, K2CO, Wc1, K2C1, Wc2, K2C2, Wc3, K2C3, Wc4, K2C4);
    return;
  }
  // ---- pairs part (blocks 761..1784 -> pairs blocks 0..1023) ----
  __shared__ int hist[4][48];
  __shared__ int bstart[4][48];
  __shared__ int runc[4][48];
  int pblk = blockIdx.x - 761;
  bool isBox = pblk >= 512;
  int qblk = isBox ? (pblk - 512) : pblk;
  const float* mask = isBox ? maskO : maskF;
  float* wlist = isBox ? wlO : wlF;
  int* plist = isBox ? plO : plF;
  int* cnt = isBox ? cntO : cntF;

  int wv = t >> 6;
  int lane = t & 63;
  int q = qblk * 4 + wv;
  int b = q >> 9;
  // recompute p1(q) bit-identical to setup_body (R1/R2-proven)
  float qv1x = v0[q*2]   + 0.1f*a[q*2];
  float qv1y = v0[q*2+1] + 0.1f*a[q*2+1];
  float qx = p0[q*2]   + 0.1f*(v0[q*2]  +qv1x)*0.5f;
  float qy = p0[q*2+1] + 0.1f*(v0[q*2+1]+qv1y)*0.5f;
  const float* mb = mask + (size_t)q*512;
  float* wl = wlist + (size_t)q*512;
  int* pl = plist + (size_t)q*512;

  if (lane < 48) { hist[wv][lane] = 0; runc[wv][lane] = 0; }

  float wreg[8]; int kreg[8];
  unsigned char predreg[8];
  for (int ch = 0; ch < 8; ++ch) {
    int s = ch*64 + lane;
    float sx, sy;
    if (isBox) {
      sx = box[(b*512+s)*2]; sy = box[(b*512+s)*2+1];
    } else {
      int n = b*512 + s;
      float sv1x = v0[n*2]   + 0.1f*a[n*2];
      float sv1y = v0[n*2+1] + 0.1f*a[n*2+1];
      sx = p0[n*2]   + 0.1f*(v0[n*2]  +sv1x)*0.5f;
      sy = p0[n*2+1] + 0.1f*(v0[n*2+1]+sv1y)*0.5f;
    }
    float rx = sx - qx, ry = sy - qy;
    float d2 = rx*rx + ry*ry;
    float m = mb[s];
    float wi = fmaxf(1.0f - d2 / 1600.0f, 0.0f);
    float w = wi*wi*wi*m;
    bool pred = w > 0.0f;
    int k = 63;
    if (pred) {
      float dist = sqrtf(d2 + 1e-9f);
      float theta = atan2f(ry, rx);
      int rb = (int)(dist / 40.0f * 3.0f);
      rb = rb > 2 ? 2 : rb;
      float u = (theta + PI_F) / (2.0f * PI_F) * 16.0f;
      int tb = ((int)floorf(u)) & 15;
      k = rb*16 + tb;
      atomicAdd(&hist[wv][k], 1);
    }
    wreg[ch] = w; kreg[ch] = k; predreg[ch] = pred ? 1 : 0;
  }
  int cntv = (lane < 48) ? hist[wv][lane] : 0;
  int sc = cntv;
  #pragma unroll
  for (int off = 1; off < 64; off <<= 1) {
    int o = __shfl_up(sc, off);
    if (lane >= off) sc += o;
  }
  if (lane < 48) bstart[wv][lane] = sc - cntv;
  if (lane == 47) cnt[q] = sc;

  for (int ch = 0; ch < 8; ++ch) {
    bool pred = predreg[ch] != 0;
    int k = kreg[ch];
    float w = wreg[ch];
    unsigned long long mEq = __ballot(pred);
    #pragma unroll
    for (int bit = 0; bit < 6; ++bit) {
      unsigned long long mbm = __ballot((k >> bit) & 1);
      mEq &= ((k >> bit) & 1) ? mbm : ~mbm;
    }
    int rank = __popcll(mEq & ((1ull<<lane)-1ull));
    int total = __popcll(mEq);
    if (pred) {
      int bs = bstart[wv][k];
      int rc = runc[wv][k];
      int pos = bs + rc + rank;
      int s = ch*64 + lane;
      wl[pos] = w;
      pl[pos] = (s<<6) | k;
      if (rank == total - 1) runc[wv][k] = rc + total;
    }
  }
}

// ---------------------------------------------------------------- split helpers (run-boundary, R10/R12-proven)
__device__ __forceinline__ int find_split_at(const int* __restrict__ pls, int nnz, int target) {
  if (target >= nnz) return nnz;
  int kmid = pls[target] & 63;
  int lo = target, hi = nnz;
  while (lo < hi) {
    int m2 = (lo + hi) >> 1;
    if ((pls[m2] & 63) > kmid) hi = m2; else lo = m2 + 1;
  }
  return lo;   // first j with bin > bin[target]
}
__device__ __forceinline__ int find_split(const int* __restrict__ pls, int nnz) {
  return find_split_at(pls, nnz, nnz >> 1);
}

// ---------------------------------------------------------------- run-based accum over [jbeg, jend) (R10/R12-proven)
template<int C2>
__device__ __forceinline__ void accum_range(float* __restrict__ M, int sw, int c,
    int jbeg, int jend,
    const float* __restrict__ wls, const int* __restrict__ pls,
    const float* __restrict__ fb) {
  int len = jend - jbeg;
  if (len <= 0) return;
  const float* wp = wls + jbeg;
  const int* pp = pls + jbeg;
  constexpr int W = 16;
  float wA[W], fA[W]; int kA[W];
  #pragma unroll
  for (int j = 0; j < W; ++j) {
    bool v = j < len;
    float wv = v ? wp[j] : 0.0f;
    int p = v ? pp[j] : 0;
    wA[j] = wv; kA[j] = v ? (p & 63) : NBIN;
    fA[j] = fb[(p >> 6) * C2];
  }
  int kcur = -1;
  float acc = 0.0f;
  for (int base = 0; base < len; base += W) {
    float wB[W], fB[W]; int kB[W];
    if (base + W < len) {
      #pragma unroll
      for (int j = 0; j < W; ++j) {
        int idx = base + W + j;
        bool v = idx < len;
        float wv = v ? wp[idx] : 0.0f;
        int p = v ? pp[idx] : 0;
        wB[j] = wv; kB[j] = v ? (p & 63) : NBIN;
        fB[j] = fb[(size_t)(p >> 6) * C2];
      }
    }
    asm volatile("" ::: "memory");   // keep next-window loads issued before stores
    #pragma unroll
    for (int j = 0; j < W; ++j) {
      acc = (kA[j] == kcur ? acc : 0.0f) + wA[j] * fA[j];
      kcur = kA[j];
      M[(kcur * C2 + c) ^ sw] = acc;
    }
    #pragma unroll
    for (int j = 0; j < W; ++j) { wA[j] = wB[j]; kA[j] = kB[j]; fA[j] = fB[j]; }
  }
}

// ---------------------------------------------------------------- list staging helper
template<int QB, int TPB>
__device__ __forceinline__ void stage_lists(int q0, const int* __restrict__ csh,
    const float* __restrict__ wlist, const int* __restrict__ plist,
    float* __restrict__ wsh, int* __restrict__ psh) {
  const int t = threadIdx.x;
  for (int i = t; i < QB*128; i += TPB) {
    int qs = i >> 7, j = i & 127;
    if (j*4 < csh[qs]) {
      ((float4*)(wsh + qs*512))[j] = ((const float4*)(wlist + (size_t)(q0+qs)*512))[j];
      ((int4*)(psh + qs*512))[j]   = ((const int4*)(plist + (size_t)(q0+qs)*512))[j];
    }
  }
}

// ---------------------------------------------------------------- standalone accum -> bf16 MBUF (layer 1)
// QB=2 queries/block; per query: 4 walk-segments x C2 threads.
template<int C2, int QB, int TPB>
__global__ __launch_bounds__(TPB, 1) void accum4(const float* __restrict__ wlist,
                                                 const int* __restrict__ plist,
                                                 const int* __restrict__ cnt,
                                                 const float* __restrict__ feats,
                                                 unsigned short* __restrict__ Mout) {
  constexpr int Kd = NBIN * C2;
  constexpr int KdP = Kd + C2;          // + dummy bin-48 row
  static_assert(TPB == 4 * QB * C2, "TPB must equal 4*QB*C2");
  __shared__ float Ml[QB * KdP];
  __shared__ float wsh[QB*512];
  __shared__ int   psh[QB*512];
  __shared__ int   csh[QB];
  const int t = threadIdx.x;
  const int q0 = blockIdx.x * QB;
  for (int i = t; i < QB*KdP; i += TPB) Ml[i] = 0.0f;
  if (t < QB) csh[t] = (q0 + t < BN) ? cnt[q0 + t] : 0;
  __syncthreads();
  stage_lists<QB, TPB>(q0, csh, wlist, plist, wsh, psh);
  __syncthreads();
  {
    const int ql = t / (4*C2);
    const int rem = t % (4*C2);
    const int seg = rem / C2, c = rem % C2;
    const int q = q0 + ql;
    const int nnz = csh[ql];
    const int* pls = psh + ql*512;
    int b0 = (seg == 0) ? 0 : find_split_at(pls, nnz, (nnz*seg) >> 2);
    int b1 = (seg == 3) ? nnz : find_split_at(pls, nnz, (nnz*(seg+1)) >> 2);
    accum_range<C2>(Ml + ql*KdP, 0, c, b0, b1,
                    wsh + ql*512, pls,
                    feats + (size_t)(q >> 9)*512*C2 + c);
  }
  __syncthreads();
  for (int i = t; i < QB*(Kd/2); i += TPB) {
    int ql = i / (Kd/2), off = i % (Kd/2);
    float2 v = ((const float2*)(Ml + ql*KdP))[off];
    ((unsigned*)(Mout + (size_t)(q0+ql)*Kd))[off] =
        (unsigned)f2bf(v.x) | ((unsigned)f2bf(v.y) << 16);
  }
}

// ---------------------------------------------------------------- bf16 MFMA GEMM with k-split (R0-proven)
template<int CT>
__global__ __launch_bounds__(256) void gemm_mfma(const unsigned short* __restrict__ A,
                                                 const unsigned short* __restrict__ B,
                                                 float* __restrict__ G, int Kd, int kn) {
  const int lane = threadIdx.x & 63;
  const int w = threadIdx.x >> 6;
  const int mblk = blockIdx.x;
  const int ks = blockIdx.y * 4 + w;
  const int k0 = ks * kn;
  const int m = lane & 15, quad = lane >> 4;
  constexpr int NT = CT / 16;
  const unsigned short* Ar0 = A + (size_t)(mblk*32 + m) * Kd + k0 + quad*8;
  const unsigned short* Ar1 = Ar0 + (size_t)16 * Kd;
  const unsigned short* Bp[NT];
  #pragma unroll
  for (int nt = 0; nt < NT; ++nt)
    Bp[nt] = B + (size_t)(nt*16 + m) * Kd + k0 + quad*8;
  v4f acc[2][NT];
  #pragma unroll
  for (int mt = 0; mt < 2; ++mt)
    for (int nt = 0; nt < NT; ++nt)
      acc[mt][nt] = (v4f){0.0f, 0.0f, 0.0f, 0.0f};
  for (int kt = 0; kt < kn; kt += 32) {
    v8s a0 = *(const v8s*)(Ar0 + kt);
    v8s a1 = *(const v8s*)(Ar1 + kt);
    #pragma unroll
    for (int nt = 0; nt < NT; ++nt) {
      v8s bv = *(const v8s*)(Bp[nt] + kt);
      acc[0][nt] = __builtin_amdgcn_mfma_f32_16x16x32_bf16(a0, bv, acc[0][nt], 0, 0, 0);
      acc[1][nt] = __builtin_amdgcn_mfma_f32_16x16x32_bf16(a1, bv, acc[1][nt], 0, 0, 0);
    }
  }
  float* Gb = G + ((size_t)ks * BN + mblk*32) * CT;
  #pragma unroll
  for (int mt = 0; mt < 2; ++mt)
    for (int nt = 0; nt < NT; ++nt)
      for (int r = 0; r < 4; ++r)
        Gb[(mt*16 + quad*4 + r) * CT + nt*16 + m] = acc[mt][nt][r];
}

// ---------------------------------------------------------------- layer epilogue w/ partials (R0-proven)
__global__ void epilogueL(const float* __restrict__ Gp, int SPLIT,
                          const float* __restrict__ inPrev, int I,
                          const float* __restrict__ Ad, const float* __restrict__ Bd,
                          const float* __restrict__ prevOut, int doRes,
                          float* __restrict__ outCur, float* __restrict__ inNext) {
  int idx = blockIdx.x * blockDim.x + threadIdx.x;
  if (idx >= BN*32) return;
  int o = idx % 32, q = idx / 32;
  float x = 0.0f, y = 0.0f;
  for (int sp = 0; sp < SPLIT; ++sp) {
    size_t base = ((size_t)sp*BN + q)*64 + o*2;
    x += Gp[base]; y += Gp[base+1];
  }
  const float* f = inPrev + (size_t)q * I * 2;
  for (int i = 0; i < I; ++i) {
    float fx = f[i*2], fy = f[i*2+1];
    float Av = Ad[o*I+i], Bv = Bd[o*I+i];
    x += Av*fx - Bv*fy;
    y += Av*fy + Bv*fx;
  }
  if (doRes) {
    x += prevOut[(size_t)idx*2];
    y += prevOut[(size_t)idx*2+1];
  }
  outCur[(size_t)idx*2]   = x;
  outCur[(size_t)idx*2+1] = y;
  float m = x*x + y*y + 1e-6f;
  float sc = fmaxf(m - 0.2f, 0.0f) / m;
  inNext[(size_t)idx*2]   = x * sc;
  inNext[(size_t)idx*2+1] = y * sc;
}

// ---------------------------------------------------------------- fused stage-0 (QB=4, 512 thr, split walks) -- R12-proven
__global__ __launch_bounds__(512, 1) void fused_s0(
    const float* __restrict__ wlF, const int* __restrict__ plF, const int* __restrict__ cntF,
    const float* __restrict__ F0, const unsigned short* __restrict__ K2CF,
    const float* __restrict__ wlO, const int* __restrict__ plO, const int* __restrict__ cntO,
    const float* __restrict__ boxf, const float* __restrict__ K2CO,
    const float* __restrict__ Adf, const float* __restrict__ Bdf,
    float* __restrict__ in1) {
  constexpr int QB = 4;
  constexpr int Kd = 2304;      // 48 bins * C2=48
  constexpr int KdP = 2352;     // + dummy row
  constexpr int NWv = 8;
  constexpr int KW = Kd / NWv;  // 288
  __shared__ float Ml[QB * KdP];
  __shared__ float Mo[QB * 98];
  __shared__ float red[NWv][QB * 32];
  __shared__ float wshF[QB*512];
  __shared__ int   pshF[QB*512];
  __shared__ float wshO[QB*512];
  __shared__ int   pshO[QB*512];
  __shared__ int cshF[QB];
  __shared__ int cshO[QB];
  const int t = threadIdx.x;
  const int q0 = blockIdx.x * QB;
  for (int i = t; i < QB*KdP; i += 512) Ml[i] = 0.0f;
  for (int i = t; i < QB*98; i += 512) Mo[i] = 0.0f;
  if (t < QB) cshF[t] = cntF[q0 + t];
  else if (t < 2*QB) cshO[t-QB] = cntO[q0 + t - QB];
  __syncthreads();
  for (int i = t; i < 2*QB*128; i += 512) {
    int half = i >> 9;
    int qs = (i >> 7) & (QB-1), j = i & 127;
    if (half == 0) {
      if (j*4 < cshF[qs]) {
        ((float4*)(wshF + qs*512))[j] = ((const float4*)(wlF + (size_t)(q0+qs)*512))[j];
        ((int4*)(pshF + qs*512))[j]   = ((const int4*)(plF + (size_t)(q0+qs)*512))[j];
      }
    } else {
      if (j*4 < cshO[qs]) {
        ((float4*)(wshO + qs*512))[j] = ((const float4*)(wlO + (size_t)(q0+qs)*512))[j];
        ((int4*)(pshO + qs*512))[j]   = ((const int4*)(plO + (size_t)(q0+qs)*512))[j];
      }
    }
  }
  __syncthreads();
  if (t < 384) {                      // fluid: 4 q x 2 halves x 48 ch
    const int ql = t / 96, rem = t % 96;
    const int half = rem / 48, c = rem % 48;
    const int q = q0 + ql;
    const int nnz = cshF[ql];
    const int js = find_split(pshF + ql*512, nnz);
    accum_range<48>(Ml + ql*KdP, ql << 2, c, half ? js : 0, half ? nnz : js,
                    wshF + ql*512, pshF + ql*512,
                    F0 + (size_t)(q >> 9)*512*48 + c);
  } else if (t < 400) {               // box: 4 q x 2 halves x 2 ch
    const int idx = t - 384;
    const int ql = idx >> 2, half = (idx >> 1) & 1, c = idx & 1;
    const int q = q0 + ql;
    const int nnz = cshO[ql];
    const int js = find_split(pshO + ql*512, nnz);
    accum_range<2>(Mo + ql*98, 0, c, half ? js : 0, half ? nnz : js,
                   wshO + ql*512, pshO + ql*512,
                   boxf + (size_t)(q >> 9)*1024 + c);
  }
  __syncthreads();
  // fluid GEMM: 8 waves k-split, CT=32 (NT=2), A rows duplicated mod 4; A/B prefetched
  {
    const int lane = t & 63, w = t >> 6;
    const int m = lane & 15, quad = lane >> 4;
    const int ar = m & 3;
    const int sw = ar << 2;
    const float* Abase = Ml + ar * KdP;
    const int kb = w * KW + quad * 8;
    const unsigned short* Bb0 = K2CF + (size_t)m * Kd + kb;
    const unsigned short* Bb1 = K2CF + (size_t)(16 + m) * Kd + kb;
    v4f acc[2];
    acc[0] = (v4f){0,0,0,0}; acc[1] = (v4f){0,0,0,0};
    float4 a0c = *(const float4*)(Abase + (kb ^ sw));
    float4 a1c = *(const float4*)(Abase + ((kb + 4) ^ sw));
    v8s b0c = *(const v8s*)(Bb0);
    v8s b1c = *(const v8s*)(Bb1);
    for (int kt = 0; kt < KW; kt += 32) {
      float4 a0n, a1n; v8s b0n, b1n;
      if (kt + 32 < KW) {
        const int jn = kb + kt + 32;
        a0n = *(const float4*)(Abase + (jn ^ sw));
        a1n = *(const float4*)(Abase + ((jn + 4) ^ sw));
        b0n = *(const v8s*)(Bb0 + kt + 32);
        b1n = *(const v8s*)(Bb1 + kt + 32);
      }
      v8s av;
      av[0]=(short)f2bf(a0c.x); av[1]=(short)f2bf(a0c.y); av[2]=(short)f2bf(a0c.z); av[3]=(short)f2bf(a0c.w);
      av[4]=(short)f2bf(a1c.x); av[5]=(short)f2bf(a1c.y); av[6]=(short)f2bf(a1c.z); av[7]=(short)f2bf(a1c.w);
      acc[0] = __builtin_amdgcn_mfma_f32_16x16x32_bf16(av, b0c, acc[0], 0, 0, 0);
      acc[1] = __builtin_amdgcn_mfma_f32_16x16x32_bf16(av, b1c, acc[1], 0, 0, 0);
      a0c = a0n; a1c = a1n; b0c = b0n; b1c = b1n;
    }
    if (quad == 0) {
      #pragma unroll
      for (int nt = 0; nt < 2; ++nt)
        #pragma unroll
        for (int r = 0; r < 4; ++r)
          red[w][r*32 + nt*16 + m] = acc[nt][r];
    }
  }
  __syncthreads();
  // epilogue0: 4 q x 48 ch
  if (t < 192) {
    const int ql = t / 48, ch = t % 48;
    const int q = q0 + ql;
    float x = 0.0f, y = 0.0f;
    if (ch < 16) {
      const float* Mq = Mo + ql*98;
      for (int j = 0; j < 96; ++j) {
        float mv = Mq[j];
        x += mv * K2CO[j*32 + ch*2];
        y += mv * K2CO[j*32 + ch*2 + 1];
      }
    } else if (ch < 32) {
      int o = ch - 16;
      #pragma unroll
      for (int w2 = 0; w2 < NWv; ++w2) {
        x += red[w2][ql*32 + o*2];
        y += red[w2][ql*32 + o*2 + 1];
      }
    } else {
      int o = ch - 32;
      const float* f = F0 + (size_t)q*48;
      for (int i = 0; i < 20; ++i) {
        float fx = f[i*2], fy = f[i*2+1];
        float Av = Adf[o*20+i], Bv = Bdf[o*20+i];
        x += Av*fx - Bv*fy;
        y += Av*fy + Bv*fx;
      }
    }
    float mm = x*x + y*y + 1e-6f;
    float sc = fmaxf(mm - 0.2f, 0.0f) / mm;
    size_t idx = (size_t)q*48 + ch;
    in1[idx*2]   = x * sc;
    in1[idx*2+1] = y * sc;
  }
}

// ---------------------------------------------------------------- fused layer (QB=4, 512 thr, split walks) -- R12-proven
template<int C2, int CT, int I, int QB>
__global__ __launch_bounds__(2*C2*QB, 1) void fused_layer(
    const float* __restrict__ wlist, const int* __restrict__ plist,
    const int* __restrict__ cnt, const float* __restrict__ feats,
    const unsigned short* __restrict__ K2T,
    const float* __restrict__ Ad, const float* __restrict__ Bd,
    const float* __restrict__ prevOut, int doRes,
    float* __restrict__ outCur, float* __restrict__ inNext) {
  constexpr int Kd = NBIN * C2;
  constexpr int KdP = Kd + C2;        // dummy row
  constexpr int TPB = 2 * C2 * QB;    // 512 for C2=64,QB=4
  constexpr int NW = TPB / 64;        // 8
  constexpr int KW = Kd / NW;         // 384
  constexpr int NT = CT / 16;
  static_assert(KW % 32 == 0, "KW must be multiple of 32");
  __shared__ float Ml[QB * KdP];
  __shared__ float red[NW][QB * CT];
  __shared__ float wsh[QB*512];
  __shared__ int   psh[QB*512];
  __shared__ int csh[QB];
  const int t = threadIdx.x;
  const int q0 = blockIdx.x * QB;
  for (int i = t; i < QB*KdP; i += TPB) Ml[i] = 0.0f;
  if (t < QB) csh[t] = cnt[q0 + t];
  __syncthreads();
  stage_lists<QB, TPB>(q0, csh, wlist, plist, wsh, psh);
  __syncthreads();
  {
    const int ql = t / (2*C2);
    const int rem = t % (2*C2);
    const int half = rem / C2, c = rem % C2;
    const int q = q0 + ql;
    const int nnz = csh[ql];
    const int js = find_split(psh + ql*512, nnz);
    accum_range<C2>(Ml + ql*KdP, (ql & 3) << 2, c, half ? js : 0, half ? nnz : js,
                    wsh + ql*512, psh + ql*512,
                    feats + (size_t)(q >> 9)*512*C2 + c);
  }
  __syncthreads();
  // GEMM: NW waves k-split; A rows duplicated mod QB; A/B prefetched one step ahead
  const int lane = t & 63, w = t >> 6;
  const int m = lane & 15, quad = lane >> 4;
  const int ar = m & (QB-1);
  const int sw = ar << 2;
  const float* Abase = Ml + ar * KdP;
  const int kb = w * KW + quad * 8;
  const unsigned short* Bb[NT];
  #pragma unroll
  for (int nt = 0; nt < NT; ++nt)
    Bb[nt] = K2T + (size_t)(nt*16 + m) * Kd + kb;
  v4f acc[NT];
  #pragma unroll
  for (int nt = 0; nt < NT; ++nt) acc[nt] = (v4f){0,0,0,0};
  float4 a0c = *(const float4*)(Abase + (kb ^ sw));
  float4 a1c = *(const float4*)(Abase + ((kb + 4) ^ sw));
  v8s bc[NT];
  #pragma unroll
  for (int nt = 0; nt < NT; ++nt) bc[nt] = *(const v8s*)(Bb[nt]);
  for (int kt = 0; kt < KW; kt += 32) {
    float4 a0n, a1n; v8s bn[NT];
    if (kt + 32 < KW) {
      const int jn = kb + kt + 32;
      a0n = *(const float4*)(Abase + (jn ^ sw));
      a1n = *(const float4*)(Abase + ((jn + 4) ^ sw));
      #pragma unroll
      for (int nt = 0; nt < NT; ++nt) bn[nt] = *(const v8s*)(Bb[nt] + kt + 32);
    }
    v8s av;
    av[0]=(short)f2bf(a0c.x); av[1]=(short)f2bf(a0c.y); av[2]=(short)f2bf(a0c.z); av[3]=(short)f2bf(a0c.w);
    av[4]=(short)f2bf(a1c.x); av[5]=(short)f2bf(a1c.y); av[6]=(short)f2bf(a1c.z); av[7]=(short)f2bf(a1c.w);
    #pragma unroll
    for (int nt = 0; nt < NT; ++nt)
      acc[nt] = __builtin_amdgcn_mfma_f32_16x16x32_bf16(av, bc[nt], acc[nt], 0, 0, 0);
    a0c = a0n; a1c = a1n;
    #pragma unroll
    for (int nt = 0; nt < NT; ++nt) bc[nt] = bn[nt];
  }
  if (quad == 0) {
    #pragma unroll
    for (int nt = 0; nt < NT; ++nt)
      #pragma unroll
      for (int r = 0; r < QB; ++r)
        red[w][r*CT + nt*16 + m] = acc[nt][r];
  }
  __syncthreads();
  // epilogue: QB * (CT/2) threads
  if (t < QB * (CT/2)) {
    const int o = t % (CT/2), ql = t / (CT/2);
    const int q = q0 + ql;
    float x = 0.0f, y = 0.0f;
    #pragma unroll
    for (int w2 = 0; w2 < NW; ++w2) {
      x += red[w2][ql*CT + o*2];
      y += red[w2][ql*CT + o*2 + 1];
    }
    const float* f = feats + (size_t)q * C2;
    for (int i = 0; i < I; ++i) {
      float fx = f[i*2], fy = f[i*2+1];
      float Av = Ad[o*I + i], Bv = Bd[o*I + i];
      x += Av*fx - Bv*fy;
      y += Av*fy + Bv*fx;
    }
    size_t idx = (size_t)q * (CT/2) + o;
    if (doRes) { x += prevOut[idx*2]; y += prevOut[idx*2+1]; }
    outCur[idx*2]   = x;
    outCur[idx*2+1] = y;
    float mm = x*x + y*y + 1e-6f;
    float sc = fmaxf(mm - 0.2f, 0.0f) / mm;
    inNext[idx*2]   = x * sc;
    inNext[idx*2+1] = y * sc;
  }
}

// ---------------------------------------------------------------- fused layer 4 (QB=4, 1024 thr, 4-way splits)
__global__ __launch_bounds__(1024, 1) void fused_l4(
    const float* __restrict__ wl, const int* __restrict__ pl, const int* __restrict__ cnt,
    const float* __restrict__ in4, const float* __restrict__ K2C4,
    const float* __restrict__ Ad4, const float* __restrict__ Bd4,
    const float* __restrict__ p1, const float* __restrict__ p0,
    float* __restrict__ dout) {
  constexpr int QB = 4, Kd = 3072, KdP = 3136;
  __shared__ float Ml[QB * KdP];
  __shared__ float wsh[QB*512];
  __shared__ int   psh[QB*512];
  __shared__ int csh[QB];
  __shared__ float r4[QB][4][2];
  const int t = threadIdx.x;
  const int q0 = blockIdx.x * QB;
  for (int i = t; i < QB*KdP; i += 1024) Ml[i] = 0.0f;
  if (t < QB) csh[t] = cnt[q0 + t];
  __syncthreads();
  stage_lists<QB, 1024>(q0, csh, wl, pl, wsh, psh);
  __syncthreads();
  {
    const int ql = t / 256, rem = t % 256;
    const int seg = rem / 64, c = rem % 64;
    const int q = q0 + ql;
    const int nnz = csh[ql];
    const int* pls = psh + ql*512;
    int b0 = (seg == 0) ? 0 : find_split_at(pls, nnz, (nnz*seg) >> 2);
    int b1 = (seg == 3) ? nnz : find_split_at(pls, nnz, (nnz*(seg+1)) >> 2);
    accum_range<64>(Ml + ql*KdP, (ql & 3) << 2, c, b0, b1,
                    wsh + ql*512, pls,
                    in4 + (size_t)(q >> 9)*512*64 + c);
  }
  __syncthreads();
  const int lane = t & 63, w = t >> 6;      // 16 waves: 4 q x 4 k-quarters
  const int ql = w >> 2, kq = w & 3;
  const int q = q0 + ql;
  const int sw = ql << 2;
  const float* Mq = Ml + ql*KdP;
  float a0 = 0.0f, a1 = 0.0f;
  for (int j = kq*768 + lane; j < kq*768 + 768; j += 64) {
    float av = Mq[j ^ sw];
    a0 += av * K2C4[j*2];
    a1 += av * K2C4[j*2+1];
  }
  if (kq == 0 && lane < 32) {
    float fx = in4[q*64 + lane*2], fy = in4[q*64 + lane*2 + 1];
    float Av = Ad4[lane], Bv = Bd4[lane];
    a0 += Av*fx - Bv*fy;
    a1 += Av*fy + Bv*fx;
  }
  for (int off = 32; off > 0; off >>= 1) {
    a0 += __shfl_down(a0, off);
    a1 += __shfl_down(a1, off);
  }
  if (lane == 0) { r4[ql][kq][0] = a0; r4[ql][kq][1] = a1; }
  __syncthreads();
  if (t < QB) {
    int qq = q0 + t;
    float s0 = r4[t][0][0] + r4[t][1][0] + r4[t][2][0] + r4[t][3][0];
    float s1 = r4[t][0][1] + r4[t][1][1] + r4[t][2][1] + r4[t][3][1];
    float px = p1[qq*2]   + s0/128.0f;
    float py = p1[qq*2+1] + s1/128.0f;
    dout[qq*2] = px; dout[qq*2+1] = py;
    dout[4096 + qq*2]   = (px - p0[qq*2]) / 0.1f;
    dout[4096 + qq*2+1] = (py - p0[qq*2+1]) / 0.1f;
  }
}

// ---------------------------------------------------------------- launch
extern "C" void kernel_launch(void* const* d_in, const int* in_sizes, int n_in,
                              void* d_out, int out_size, void* d_ws, size_t ws_size,
                              hipStream_t stream) {
  (void)in_sizes; (void)n_in; (void)out_size; (void)ws_size;
  const float* v0_enc = (const float*)d_in[1];
  const float* p0     = (const float*)d_in[2];
  const float* v0     = (const float*)d_in[3];
  const float* a      = (const float*)d_in[4];
  const float* other  = (const float*)d_in[5];
  const float* box    = (const float*)d_in[6];
  const float* boxf   = (const float*)d_in[7];
  const float* fmask  = (const float*)d_in[8];
  const float* bmask  = (const float*)d_in[9];
  const float* Wcf = (const float*)d_in[10];
  const float* Wco = (const float*)d_in[11];
  const float* Adf = (const float*)d_in[12];
  const float* Bdf = (const float*)d_in[13];
  const float* Wc1 = (const float*)d_in[14];
  const float* Ad1 = (const float*)d_in[15];
  const float* Bd1 = (const float*)d_in[16];
  const float* Wc2 = (const float*)d_in[17];
  const float* Ad2 = (const float*)d_in[18];
  const float* Bd2 = (const float*)d_in[19];
  const float* Wc3 = (const float*)d_in[20];
  const float* Ad3 = (const float*)d_in[21];
  const float* Bd3 = (const float*)d_in[22];
  const float* Wc4 = (const float*)d_in[23];
  const float* Ad4 = (const float*)d_in[24];
  const float* Bd4 = (const float*)d_in[25];

  float* ws = (float*)d_ws;
  float* P1    = ws + 0;          // 4096
  float* F0    = ws + 4096;       // 98304  (stride 48, padded)
  unsigned short* K2CF = (unsigned short*)(ws + 102400);  // [32][2304] bf16 T
  float* K2CO  = ws + 176128;     // [96][32] fp32
  unsigned short* K2C1 = (unsigned short*)(ws + 179200);  // [64][4608] bf16 T
  unsigned short* K2C2 = (unsigned short*)(ws + 474112);  // [64][3072] bf16 T
  unsigned short* K2C3 = (unsigned short*)(ws + 670720);
  float* K2C4  = ws + 867328;     // [3072][2] fp32
  float* WFl   = ws + 873472;     // 1048576
  int*   PFl   = (int*)(ws + 1922048);   // 1048576
  int*   CNTF  = (int*)(ws + 2970624);   // 2048
  int*   CNTO  = (int*)(ws + 2972672);   // 2048
  float* IN1   = ws + 2974720;    // 196608 (2048 x 96)
  float* IN2   = ws + 3171328;    // 131072
  float* IN3   = ws + 3302400;    // 131072
  float* IN4   = ws + 3433472;    // 131072
  float* OUTA  = ws + 3564544;    // 131072
  float* OUTB  = ws + 3695616;    // 131072
  float* GPART = ws + 4027392;    // 16 x 2048 x 64 fp32 (L1 k-split partials)
  unsigned short* MBUF = (unsigned short*)(ws + 6124544); // bf16 2048 x 4608
  float* WOl   = ws + 15561728;   // 1048576
  int*   POl   = (int*)(ws + 16610304);  // 1048576

  // 1: merged setup (P1/F0/steer tables) + pairs (self-sufficient p1, bin-sorted)
  setup_pairs<<<1785, 256, 0, stream>>>(p0, v0, a, other, v0_enc, P1, F0,
                                        Wcf, K2CF, Wco, K2CO, Wc1, K2C1,
                                        Wc2, K2C2, Wc3, K2C3, Wc4, K2C4,
                                        fmask, WFl, PFl, CNTF,
                                        box, bmask, WOl, POl, CNTO);
  // 2: stage 0 fused -> IN1
  fused_s0<<<512, 512, 0, stream>>>(WFl, PFl, CNTF, F0, K2CF,
                                    WOl, POl, CNTO, boxf, K2CO, Adf, Bdf, IN1);
  // 3: layer 1 (I=48 -> O=32): accum (4-way split) -> MBUF, tiled MFMA GEMM, epilogue
  accum4<96, 2, 768><<<1024, 768, 0, stream>>>(WFl, PFl, CNTF, IN1, MBUF);
  gemm_mfma<64><<<dim3(64, 4), 256, 0, stream>>>(MBUF, K2C1, GPART, 4608, 288); // SPLIT=16
  epilogueL<<<256, 256, 0, stream>>>(GPART, 16, IN1, 48, Ad1, Bd1, nullptr, 0, OUTA, IN2);
  // 4: layer 2 (I=32 -> O=32, residual)
  fused_layer<64, 64, 32, 4><<<512, 512, 0, stream>>>(WFl, PFl, CNTF, IN2, K2C2,
                                                      Ad2, Bd2, OUTA, 1, OUTB, IN3);
  // 5: layer 3 (I=32 -> O=32, residual)
  fused_layer<64, 64, 32, 4><<<512, 512, 0, stream>>>(WFl, PFl, CNTF, IN3, K2C3,
                                                      Ad3, Bd3, OUTB, 1, OUTA, IN4);
  // 6: layer 4 fused thin GEMM + apply_correction (4-way splits)
  fused_l4<<<512, 1024, 0, stream>>>(WFl, PFl, CNTF, IN4, K2C4, Ad4, Bd4,
                                     P1, p0, (float*)d_out);
}

// Round 14
// 291.155 us; speedup vs baseline: 1.0121x; 1.0121x over previous
//
#include <hip/hip_runtime.h>
#include <cstdint>
#include <cstddef>

#define PI_F 3.14159265358979323846f

constexpr int BB = 4, NN = 512, BN = 2048, NBIN = 48;

typedef __attribute__((ext_vector_type(8))) short v8s;   // 8 bf16 (4 VGPRs)
typedef __attribute__((ext_vector_type(4))) float v4f;   // MFMA acc

__device__ __forceinline__ unsigned short f2bf(float f) {
  unsigned u = __float_as_uint(f);
  unsigned r = (u + 0x7FFFu + ((u >> 16) & 1u)) >> 16;   // RNE
  return (unsigned short)r;
}
__device__ __forceinline__ float bf2f(unsigned short s) {
  return __uint_as_float(((unsigned)s) << 16);
}

// ---------------------------------------------------------------- steer variants
__device__ __forceinline__ void steer_f32(const float* __restrict__ W, float* __restrict__ K2,
                                          int O, int I, int Ipad, int idx, int total) {
  if (idx >= total) return;
  int i = idx % Ipad;
  int o = (idx / Ipad) % O;
  int k = idx / (Ipad * O);
  int CTc = O * 2;
  size_t r0 = (size_t)((k*Ipad + i)*2 + 0) * CTc + o*2;
  size_t r1 = r0 + CTc;
  if (i >= I) { K2[r0]=0.f; K2[r0+1]=0.f; K2[r1]=0.f; K2[r1+1]=0.f; return; }
  int tt = k % 16;
  float ang = (tt + 0.5f) * (2.0f * PI_F / 16.0f) - PI_F;
  float ct = cosf(ang), st = sinf(ang);
  const float* Wp = W + ((size_t)(k*O + o)*I + i) * 4;
  float w00 = Wp[0], w01 = Wp[1], w10 = Wp[2], w11 = Wp[3];
  float rw00 = ct*w00 - st*w10, rw01 = ct*w01 - st*w11;
  float rw10 = st*w00 + ct*w10, rw11 = st*w01 + ct*w11;
  K2[r0 + 0] = rw00*ct - rw01*st;
  K2[r0 + 1] = rw10*ct - rw11*st;
  K2[r1 + 0] = rw00*st + rw01*ct;
  K2[r1 + 1] = rw10*st + rw11*ct;
}

__device__ __forceinline__ void steer_bf16T(const float* __restrict__ W,
                                            unsigned short* __restrict__ K2T,
                                            int O, int I, int Ipad, int Kd,
                                            int idx, int total) {
  if (idx >= total) return;
  int i = idx % Ipad;
  int o = (idx / Ipad) % O;
  int k = idx / (Ipad * O);
  size_t c0 = (size_t)(o*2 + 0) * Kd + (k*Ipad + i)*2;
  size_t c1 = (size_t)(o*2 + 1) * Kd + (k*Ipad + i)*2;
  if (i >= I) { K2T[c0]=0; K2T[c0+1]=0; K2T[c1]=0; K2T[c1+1]=0; return; }
  int tt = k % 16;
  float ang = (tt + 0.5f) * (2.0f * PI_F / 16.0f) - PI_F;
  float ct = cosf(ang), st = sinf(ang);
  const float* Wp = W + ((size_t)(k*O + o)*I + i) * 4;
  float w00 = Wp[0], w01 = Wp[1], w10 = Wp[2], w11 = Wp[3];
  float rw00 = ct*w00 - st*w10, rw01 = ct*w01 - st*w11;
  float rw10 = st*w00 + ct*w10, rw11 = st*w01 + ct*w11;
  K2T[c0 + 0] = f2bf(rw00*ct - rw01*st);
  K2T[c0 + 1] = f2bf(rw00*st + rw01*ct);
  K2T[c1 + 0] = f2bf(rw10*ct - rw11*st);
  K2T[c1 + 1] = f2bf(rw10*st + rw11*ct);
}

// ---------------------------------------------------------------- setup: prep + all steers
__global__ __launch_bounds__(256) void setup_kernel(
    const float* __restrict__ p0, const float* __restrict__ v0,
    const float* __restrict__ a, const float* __restrict__ other,
    const float* __restrict__ v0enc, float* __restrict__ p1, float* __restrict__ F0,
    const float* Wcf, unsigned short* K2CF, const float* Wco, float* K2CO,
    const float* Wc1, unsigned short* K2C1, const float* Wc2, unsigned short* K2C2,
    const float* Wc3, unsigned short* K2C3, const float* Wc4, float* K2C4) {
  int blk = blockIdx.x;
  int t = threadIdx.x;
  if (blk < 8) {
    int n = blk * 256 + t;
    float p0x = p0[n*2], p0y = p0[n*2+1];
    float v0x = v0[n*2], v0y = v0[n*2+1];
    float ax = a[n*2],  ay = a[n*2+1];
    float v1x = v0x + 0.1f*ax, v1y = v0y + 0.1f*ay;
    p1[n*2]   = p0x + 0.1f*(v0x+v1x)*0.5f;
    p1[n*2+1] = p0y + 0.1f*(v0y+v1y)*0.5f;
    float* F = F0 + (size_t)n*48;
    F[0] = v1x; F[1] = v1y;
    for (int c = 0; c < 3; ++c) {
      F[2+c*2]   = other[(n*3+c)*2];
      F[2+c*2+1] = other[(n*3+c)*2+1];
    }
    for (int c = 0; c < 16; ++c) {
      F[8+c*2]   = v0enc[(n*16+c)*2];
      F[8+c*2+1] = v0enc[(n*16+c)*2+1];
    }
    for (int c = 40; c < 48; ++c) F[c] = 0.0f;
  } else if (blk < 80)  steer_bf16T(Wcf, K2CF, 16, 20, 24, 2304, (blk-8)*256 + t, 18432);
  else if (blk < 83)  steer_f32(Wco, K2CO, 16, 1, 1,   (blk-80)*256 + t, 768);
  else if (blk < 371) steer_bf16T(Wc1, K2C1, 32, 48, 48, 4608, (blk-83)*256 + t, 73728);
  else if (blk < 563) steer_bf16T(Wc2, K2C2, 32, 32, 32, 3072, (blk-371)*256 + t, 49152);
  else if (blk < 755) steer_bf16T(Wc3, K2C3, 32, 32, 32, 3072, (blk-563)*256 + t, 49152);
  else                steer_f32(Wc4, K2C4, 1, 32, 32,  (blk-755)*256 + t, 1536);
}

// ---------------------------------------------------------------- pairs + stable bin-sorted compaction (R9-proven)
__global__ __launch_bounds__(256) void pairs_all(const float* __restrict__ qry,
                                                 const float* __restrict__ srcF,
                                                 const float* __restrict__ maskF,
                                                 float* __restrict__ wlF, int* __restrict__ plF,
                                                 int* __restrict__ cntF,
                                                 const float* __restrict__ srcO,
                                                 const float* __restrict__ maskO,
                                                 float* __restrict__ wlO, int* __restrict__ plO,
                                                 int* __restrict__ cntO) {
  __shared__ int hist[4][48];
  __shared__ int bstart[4][48];
  __shared__ int runc[4][48];
  bool isBox = blockIdx.x >= 512;
  int qblk = isBox ? (blockIdx.x - 512) : blockIdx.x;
  const float* src = isBox ? srcO : srcF;
  const float* mask = isBox ? maskO : maskF;
  float* wlist = isBox ? wlO : wlF;
  int* plist = isBox ? plO : plF;
  int* cnt = isBox ? cntO : cntF;

  int wv = threadIdx.x >> 6;
  int lane = threadIdx.x & 63;
  int q = qblk * 4 + wv;
  int b = q >> 9;
  float qx = qry[q*2], qy = qry[q*2+1];
  const float* sb = src + b*1024;
  const float* mb = mask + (size_t)q*512;
  float* wl = wlist + (size_t)q*512;
  int* pl = plist + (size_t)q*512;

  if (lane < 48) { hist[wv][lane] = 0; runc[wv][lane] = 0; }

  float wreg[8]; int kreg[8];
  unsigned char predreg[8];
  for (int ch = 0; ch < 8; ++ch) {
    int s = ch*64 + lane;
    float sx = sb[s*2], sy = sb[s*2+1];
    float rx = sx - qx, ry = sy - qy;
    float d2 = rx*rx + ry*ry;
    float m = mb[s];
    float wi = fmaxf(1.0f - d2 / 1600.0f, 0.0f);
    float w = wi*wi*wi*m;
    bool pred = w > 0.0f;
    int k = 63;
    if (pred) {
      float dist = sqrtf(d2 + 1e-9f);
      float theta = atan2f(ry, rx);
      int rb = (int)(dist / 40.0f * 3.0f);
      rb = rb > 2 ? 2 : rb;
      float u = (theta + PI_F) / (2.0f * PI_F) * 16.0f;
      int tb = ((int)floorf(u)) & 15;
      k = rb*16 + tb;
      atomicAdd(&hist[wv][k], 1);
    }
    wreg[ch] = w; kreg[ch] = k; predreg[ch] = pred ? 1 : 0;
  }
  int cntv = (lane < 48) ? hist[wv][lane] : 0;
  int sc = cntv;
  #pragma unroll
  for (int off = 1; off < 64; off <<= 1) {
    int o = __shfl_up(sc, off);
    if (lane >= off) sc += o;
  }
  if (lane < 48) bstart[wv][lane] = sc - cntv;
  if (lane == 47) cnt[q] = sc;

  for (int ch = 0; ch < 8; ++ch) {
    bool pred = predreg[ch] != 0;
    int k = kreg[ch];
    float w = wreg[ch];
    unsigned long long mEq = __ballot(pred);
    #pragma unroll
    for (int bit = 0; bit < 6; ++bit) {
      unsigned long long mbm = __ballot((k >> bit) & 1);
      mEq &= ((k >> bit) & 1) ? mbm : ~mbm;
    }
    int rank = __popcll(mEq & ((1ull<<lane)-1ull));
    int total = __popcll(mEq);
    if (pred) {
      int bs = bstart[wv][k];
      int rc = runc[wv][k];
      int pos = bs + rc + rank;
      int s = ch*64 + lane;
      wl[pos] = w;
      pl[pos] = (s<<6) | k;
      if (rank == total - 1) runc[wv][k] = rc + total;
    }
  }
}

// ---------------------------------------------------------------- split point: end of run containing median (R10-proven)
__device__ __forceinline__ int find_split(const int* __restrict__ pls, int nnz) {
  if (nnz <= 0) return 0;
  int kmid = pls[nnz >> 1] & 63;
  int lo = nnz >> 1, hi = nnz;
  while (lo < hi) {
    int m2 = (lo + hi) >> 1;
    if ((pls[m2] & 63) > kmid) hi = m2; else lo = m2 + 1;
  }
  return lo;   // first j with bin > kmid
}

// ---------------------------------------------------------------- run-based accum over [jbeg, jend) (R10-proven scalar)
// Sorted lists -> register run accumulation, write-only LDS. Padding writes go to
// dummy bin 48 (slab stride (NBIN+1)*C2). Per-bin add order = s order (stable sort,
// runs not split across halves) -> bit-identical sums.
template<int C2>
__device__ __forceinline__ void accum_range(float* __restrict__ M, int sw, int c,
    int jbeg, int jend,
    const float* __restrict__ wls, const int* __restrict__ pls,
    const float* __restrict__ fb) {
  int len = jend - jbeg;
  if (len <= 0) return;
  const float* wp = wls + jbeg;
  const int* pp = pls + jbeg;
  constexpr int W = 16;
  float wA[W], fA[W]; int kA[W];
  #pragma unroll
  for (int j = 0; j < W; ++j) {
    bool v = j < len;
    float wv = v ? wp[j] : 0.0f;
    int p = v ? pp[j] : 0;
    wA[j] = wv; kA[j] = v ? (p & 63) : NBIN;
    fA[j] = fb[(p >> 6) * C2];
  }
  int kcur = -1;
  float acc = 0.0f;
  for (int base = 0; base < len; base += W) {
    float wB[W], fB[W]; int kB[W];
    if (base + W < len) {
      #pragma unroll
      for (int j = 0; j < W; ++j) {
        int idx = base + W + j;
        bool v = idx < len;
        float wv = v ? wp[idx] : 0.0f;
        int p = v ? pp[idx] : 0;
        wB[j] = wv; kB[j] = v ? (p & 63) : NBIN;
        fB[j] = fb[(size_t)(p >> 6) * C2];
      }
    }
    asm volatile("" ::: "memory");   // keep next-window loads issued before stores
    #pragma unroll
    for (int j = 0; j < W; ++j) {
      acc = (kA[j] == kcur ? acc : 0.0f) + wA[j] * fA[j];
      kcur = kA[j];
      M[(kcur * C2 + c) ^ sw] = acc;
    }
    #pragma unroll
    for (int j = 0; j < W; ++j) { wA[j] = wB[j]; kA[j] = kB[j]; fA[j] = fB[j]; }
  }
}

// ---------------------------------------------------------------- list staging helper
template<int QB, int TPB>
__device__ __forceinline__ void stage_lists(int q0, const int* __restrict__ csh,
    const float* __restrict__ wlist, const int* __restrict__ plist,
    float* __restrict__ wsh, int* __restrict__ psh) {
  const int t = threadIdx.x;
  for (int i = t; i < QB*128; i += TPB) {
    int qs = i >> 7, j = i & 127;
    if (j*4 < csh[qs]) {
      ((float4*)(wsh + qs*512))[j] = ((const float4*)(wlist + (size_t)(q0+qs)*512))[j];
      ((int4*)(psh + qs*512))[j]   = ((const int4*)(plist + (size_t)(q0+qs)*512))[j];
    }
  }
}

// ---------------------------------------------------------------- standalone accum -> bf16 MBUF (layer 1)
// QB=2 queries/block; per query: 2 walk-halves x C2 threads (1 channel each).
template<int C2, int QB, int TPB>
__global__ __launch_bounds__(TPB, 1) void accum4(const float* __restrict__ wlist,
                                                 const int* __restrict__ plist,
                                                 const int* __restrict__ cnt,
                                                 const float* __restrict__ feats,
                                                 unsigned short* __restrict__ Mout) {
  constexpr int Kd = NBIN * C2;
  constexpr int KdP = Kd + C2;          // + dummy bin-48 row
  static_assert(TPB == 2 * QB * C2, "TPB must equal 2*QB*C2");
  __shared__ float Ml[QB * KdP];
  __shared__ float wsh[QB*512];
  __shared__ int   psh[QB*512];
  __shared__ int   csh[QB];
  const int t = threadIdx.x;
  const int q0 = blockIdx.x * QB;
  for (int i = t; i < QB*KdP; i += TPB) Ml[i] = 0.0f;
  if (t < QB) csh[t] = (q0 + t < BN) ? cnt[q0 + t] : 0;
  __syncthreads();
  stage_lists<QB, TPB>(q0, csh, wlist, plist, wsh, psh);
  __syncthreads();
  {
    const int ql = t / (2*C2);
    const int rem = t % (2*C2);
    const int half = rem / C2, c = rem % C2;
    const int q = q0 + ql;
    const int nnz = csh[ql];
    const int js = find_split(psh + ql*512, nnz);
    accum_range<C2>(Ml + ql*KdP, 0, c, half ? js : 0, half ? nnz : js,
                    wsh + ql*512, psh + ql*512,
                    feats + (size_t)(q >> 9)*512*C2 + c);
  }
  __syncthreads();
  for (int i = t; i < QB*(Kd/2); i += TPB) {
    int ql = i / (Kd/2), off = i % (Kd/2);
    float2 v = ((const float2*)(Ml + ql*KdP))[off];
    ((unsigned*)(Mout + (size_t)(q0+ql)*Kd))[off] =
        (unsigned)f2bf(v.x) | ((unsigned)f2bf(v.y) << 16);
  }
}

// ---------------------------------------------------------------- bf16 MFMA GEMM with k-split (R0-proven)
template<int CT>
__global__ __launch_bounds__(256) void gemm_mfma(const unsigned short* __restrict__ A,
                                                 const unsigned short* __restrict__ B,
                                                 float* __restrict__ G, int Kd, int kn) {
  const int lane = threadIdx.x & 63;
  const int w = threadIdx.x >> 6;
  const int mblk = blockIdx.x;
  const int ks = blockIdx.y * 4 + w;
  const int k0 = ks * kn;
  const int m = lane & 15, quad = lane >> 4;
  constexpr int NT = CT / 16;
  const unsigned short* Ar0 = A + (size_t)(mblk*32 + m) * Kd + k0 + quad*8;
  const unsigned short* Ar1 = Ar0 + (size_t)16 * Kd;
  const unsigned short* Bp[NT];
  #pragma unroll
  for (int nt = 0; nt < NT; ++nt)
    Bp[nt] = B + (size_t)(nt*16 + m) * Kd + k0 + quad*8;
  v4f acc[2][NT];
  #pragma unroll
  for (int mt = 0; mt < 2; ++mt)
    for (int nt = 0; nt < NT; ++nt)
      acc[mt][nt] = (v4f){0.0f, 0.0f, 0.0f, 0.0f};
  for (int kt = 0; kt < kn; kt += 32) {
    v8s a0 = *(const v8s*)(Ar0 + kt);
    v8s a1 = *(const v8s*)(Ar1 + kt);
    #pragma unroll
    for (int nt = 0; nt < NT; ++nt) {
      v8s bv = *(const v8s*)(Bp[nt] + kt);
      acc[0][nt] = __builtin_amdgcn_mfma_f32_16x16x32_bf16(a0, bv, acc[0][nt], 0, 0, 0);
      acc[1][nt] = __builtin_amdgcn_mfma_f32_16x16x32_bf16(a1, bv, acc[1][nt], 0, 0, 0);
    }
  }
  float* Gb = G + ((size_t)ks * BN + mblk*32) * CT;
  #pragma unroll
  for (int mt = 0; mt < 2; ++mt)
    for (int nt = 0; nt < NT; ++nt)
      for (int r = 0; r < 4; ++r)
        Gb[(mt*16 + quad*4 + r) * CT + nt*16 + m] = acc[mt][nt][r];
}

// ---------------------------------------------------------------- layer epilogue w/ partials (R0-proven)
__global__ void epilogueL(const float* __restrict__ Gp, int SPLIT,
                          const float* __restrict__ inPrev, int I,
                          const float* __restrict__ Ad, const float* __restrict__ Bd,
                          const float* __restrict__ prevOut, int doRes,
                          float* __restrict__ outCur, float* __restrict__ inNext) {
  int idx = blockIdx.x * blockDim.x + threadIdx.x;
  if (idx >= BN*32) return;
  int o = idx % 32, q = idx / 32;
  float x = 0.0f, y = 0.0f;
  for (int sp = 0; sp < SPLIT; ++sp) {
    size_t base = ((size_t)sp*BN + q)*64 + o*2;
    x += Gp[base]; y += Gp[base+1];
  }
  const float* f = inPrev + (size_t)q * I * 2;
  for (int i = 0; i < I; ++i) {
    float fx = f[i*2], fy = f[i*2+1];
    float Av = Ad[o*I+i], Bv = Bd[o*I+i];
    x += Av*fx - Bv*fy;
    y += Av*fy + Bv*fx;
  }
  if (doRes) {
    x += prevOut[(size_t)idx*2];
    y += prevOut[(size_t)idx*2+1];
  }
  outCur[(size_t)idx*2]   = x;
  outCur[(size_t)idx*2+1] = y;
  float m = x*x + y*y + 1e-6f;
  float sc = fmaxf(m - 0.2f, 0.0f) / m;
  inNext[(size_t)idx*2]   = x * sc;
  inNext[(size_t)idx*2+1] = y * sc;
}

// ---------------------------------------------------------------- fused stage-0 (QB=4, 512 thr, split walks)
__global__ __launch_bounds__(512, 1) void fused_s0(
    const float* __restrict__ wlF, const int* __restrict__ plF, const int* __restrict__ cntF,
    const float* __restrict__ F0, const unsigned short* __restrict__ K2CF,
    const float* __restrict__ wlO, const int* __restrict__ plO, const int* __restrict__ cntO,
    const float* __restrict__ boxf, const float* __restrict__ K2CO,
    const float* __restrict__ Adf, const float* __restrict__ Bdf,
    float* __restrict__ in1) {
  constexpr int QB = 4;
  constexpr int Kd = 2304;      // 48 bins * C2=48
  constexpr int KdP = 2352;     // + dummy row
  constexpr int NWv = 8;
  constexpr int KW = Kd / NWv;  // 288
  __shared__ float Ml[QB * KdP];
  __shared__ float Mo[QB * 98];
  __shared__ float red[NWv][QB * 32];
  __shared__ float wshF[QB*512];
  __shared__ int   pshF[QB*512];
  __shared__ float wshO[QB*512];
  __shared__ int   pshO[QB*512];
  __shared__ int cshF[QB];
  __shared__ int cshO[QB];
  const int t = threadIdx.x;
  const int q0 = blockIdx.x * QB;
  for (int i = t; i < QB*KdP; i += 512) Ml[i] = 0.0f;
  for (int i = t; i < QB*98; i += 512) Mo[i] = 0.0f;
  if (t < QB) cshF[t] = cntF[q0 + t];
  else if (t < 2*QB) cshO[t-QB] = cntO[q0 + t - QB];
  __syncthreads();
  for (int i = t; i < 2*QB*128; i += 512) {
    int half = i >> 9;
    int qs = (i >> 7) & (QB-1), j = i & 127;
    if (half == 0) {
      if (j*4 < cshF[qs]) {
        ((float4*)(wshF + qs*512))[j] = ((const float4*)(wlF + (size_t)(q0+qs)*512))[j];
        ((int4*)(pshF + qs*512))[j]   = ((const int4*)(plF + (size_t)(q0+qs)*512))[j];
      }
    } else {
      if (j*4 < cshO[qs]) {
        ((float4*)(wshO + qs*512))[j] = ((const float4*)(wlO + (size_t)(q0+qs)*512))[j];
        ((int4*)(pshO + qs*512))[j]   = ((const int4*)(plO + (size_t)(q0+qs)*512))[j];
      }
    }
  }
  __syncthreads();
  if (t < 384) {                      // fluid: 4 q x 2 halves x 48 ch
    const int ql = t / 96, rem = t % 96;
    const int half = rem / 48, c = rem % 48;
    const int q = q0 + ql;
    const int nnz = cshF[ql];
    const int js = find_split(pshF + ql*512, nnz);
    accum_range<48>(Ml + ql*KdP, ql << 2, c, half ? js : 0, half ? nnz : js,
                    wshF + ql*512, pshF + ql*512,
                    F0 + (size_t)(q >> 9)*512*48 + c);
  } else if (t < 400) {               // box: 4 q x 2 halves x 2 ch
    const int idx = t - 384;
    const int ql = idx >> 2, half = (idx >> 1) & 1, c = idx & 1;
    const int q = q0 + ql;
    const int nnz = cshO[ql];
    const int js = find_split(pshO + ql*512, nnz);
    accum_range<2>(Mo + ql*98, 0, c, half ? js : 0, half ? nnz : js,
                   wshO + ql*512, pshO + ql*512,
                   boxf + (size_t)(q >> 9)*1024 + c);
  }
  __syncthreads();
  // fluid GEMM: 8 waves k-split, CT=32 (NT=2), A rows duplicated mod 4; A/B prefetched
  {
    const int lane = t & 63, w = t >> 6;
    const int m = lane & 15, quad = lane >> 4;
    const int ar = m & 3;
    const int sw = ar << 2;
    const float* Abase = Ml + ar * KdP;
    const int kb = w * KW + quad * 8;
    const unsigned short* Bb0 = K2CF + (size_t)m * Kd + kb;
    const unsigned short* Bb1 = K2CF + (size_t)(16 + m) * Kd + kb;
    v4f acc[2];
    acc[0] = (v4f){0,0,0,0}; acc[1] = (v4f){0,0,0,0};
    float4 a0c = *(const float4*)(Abase + (kb ^ sw));
    float4 a1c = *(const float4*)(Abase + ((kb + 4) ^ sw));
    v8s b0c = *(const v8s*)(Bb0);
    v8s b1c = *(const v8s*)(Bb1);
    for (int kt = 0; kt < KW; kt += 32) {
      float4 a0n, a1n; v8s b0n, b1n;
      if (kt + 32 < KW) {
        const int jn = kb + kt + 32;
        a0n = *(const float4*)(Abase + (jn ^ sw));
        a1n = *(const float4*)(Abase + ((jn + 4) ^ sw));
        b0n = *(const v8s*)(Bb0 + kt + 32);
        b1n = *(const v8s*)(Bb1 + kt + 32);
      }
      v8s av;
      av[0]=(short)f2bf(a0c.x); av[1]=(short)f2bf(a0c.y); av[2]=(short)f2bf(a0c.z); av[3]=(short)f2bf(a0c.w);
      av[4]=(short)f2bf(a1c.x); av[5]=(short)f2bf(a1c.y); av[6]=(short)f2bf(a1c.z); av[7]=(short)f2bf(a1c.w);
      acc[0] = __builtin_amdgcn_mfma_f32_16x16x32_bf16(av, b0c, acc[0], 0, 0, 0);
      acc[1] = __builtin_amdgcn_mfma_f32_16x16x32_bf16(av, b1c, acc[1], 0, 0, 0);
      a0c = a0n; a1c = a1n; b0c = b0n; b1c = b1n;
    }
    if (quad == 0) {
      #pragma unroll
      for (int nt = 0; nt < 2; ++nt)
        #pragma unroll
        for (int r = 0; r < 4; ++r)
          red[w][r*32 + nt*16 + m] = acc[nt][r];
    }
  }
  __syncthreads();
  // epilogue0: 4 q x 48 ch
  if (t < 192) {
    const int ql = t / 48, ch = t % 48;
    const int q = q0 + ql;
    float x = 0.0f, y = 0.0f;
    if (ch < 16) {
      const float* Mq = Mo + ql*98;
      for (int j = 0; j < 96; ++j) {
        float mv = Mq[j];
        x += mv * K2CO[j*32 + ch*2];
        y += mv * K2CO[j*32 + ch*2 + 1];
      }
    } else if (ch < 32) {
      int o = ch - 16;
      #pragma unroll
      for (int w2 = 0; w2 < NWv; ++w2) {
        x += red[w2][ql*32 + o*2];
        y += red[w2][ql*32 + o*2 + 1];
      }
    } else {
      int o = ch - 32;
      const float* f = F0 + (size_t)q*48;
      for (int i = 0; i < 20; ++i) {
        float fx = f[i*2], fy = f[i*2+1];
        float Av = Adf[o*20+i], Bv = Bdf[o*20+i];
        x += Av*fx - Bv*fy;
        y += Av*fy + Bv*fx;
      }
    }
    float mm = x*x + y*y + 1e-6f;
    float sc = fmaxf(mm - 0.2f, 0.0f) / mm;
    size_t idx = (size_t)q*48 + ch;
    in1[idx*2]   = x * sc;
    in1[idx*2+1] = y * sc;
  }
}

// ---------------------------------------------------------------- fused layer (QB=4, 512 thr, split walks): layers 2-3
template<int C2, int CT, int I, int QB>
__global__ __launch_bounds__(2*C2*QB, 1) void fused_layer(
    const float* __restrict__ wlist, const int* __restrict__ plist,
    const int* __restrict__ cnt, const float* __restrict__ feats,
    const unsigned short* __restrict__ K2T,
    const float* __restrict__ Ad, const float* __restrict__ Bd,
    const float* __restrict__ prevOut, int doRes,
    float* __restrict__ outCur, float* __restrict__ inNext) {
  constexpr int Kd = NBIN * C2;
  constexpr int KdP = Kd + C2;        // dummy row
  constexpr int TPB = 2 * C2 * QB;    // 512 for C2=64,QB=4
  constexpr int NW = TPB / 64;        // 8
  constexpr int KW = Kd / NW;         // 384
  constexpr int NT = CT / 16;
  static_assert(KW % 32 == 0, "KW must be multiple of 32");
  __shared__ float Ml[QB * KdP];
  __shared__ float red[NW][QB * CT];
  __shared__ float wsh[QB*512];
  __shared__ int   psh[QB*512];
  __shared__ int csh[QB];
  const int t = threadIdx.x;
  const int q0 = blockIdx.x * QB;
  for (int i = t; i < QB*KdP; i += TPB) Ml[i] = 0.0f;
  if (t < QB) csh[t] = cnt[q0 + t];
  __syncthreads();
  stage_lists<QB, TPB>(q0, csh, wlist, plist, wsh, psh);
  __syncthreads();
  {
    const int ql = t / (2*C2);
    const int rem = t % (2*C2);
    const int half = rem / C2, c = rem % C2;
    const int q = q0 + ql;
    const int nnz = csh[ql];
    const int js = find_split(psh + ql*512, nnz);
    accum_range<C2>(Ml + ql*KdP, (ql & 3) << 2, c, half ? js : 0, half ? nnz : js,
                    wsh + ql*512, psh + ql*512,
                    feats + (size_t)(q >> 9)*512*C2 + c);
  }
  __syncthreads();
  // GEMM: NW waves k-split; A rows duplicated mod QB; A/B prefetched one step ahead
  const int lane = t & 63, w = t >> 6;
  const int m = lane & 15, quad = lane >> 4;
  const int ar = m & (QB-1);
  const int sw = ar << 2;
  const float* Abase = Ml + ar * KdP;
  const int kb = w * KW + quad * 8;
  const unsigned short* Bb[NT];
  #pragma unroll
  for (int nt = 0; nt < NT; ++nt)
    Bb[nt] = K2T + (size_t)(nt*16 + m) * Kd + kb;
  v4f acc[NT];
  #pragma unroll
  for (int nt = 0; nt < NT; ++nt) acc[nt] = (v4f){0,0,0,0};
  float4 a0c = *(const float4*)(Abase + (kb ^ sw));
  float4 a1c = *(const float4*)(Abase + ((kb + 4) ^ sw));
  v8s bc[NT];
  #pragma unroll
  for (int nt = 0; nt < NT; ++nt) bc[nt] = *(const v8s*)(Bb[nt]);
  for (int kt = 0; kt < KW; kt += 32) {
    float4 a0n, a1n; v8s bn[NT];
    if (kt + 32 < KW) {
      const int jn = kb + kt + 32;
      a0n = *(const float4*)(Abase + (jn ^ sw));
      a1n = *(const float4*)(Abase + ((jn + 4) ^ sw));
      #pragma unroll
      for (int nt = 0; nt < NT; ++nt) bn[nt] = *(const v8s*)(Bb[nt] + kt + 32);
    }
    v8s av;
    av[0]=(short)f2bf(a0c.x); av[1]=(short)f2bf(a0c.y); av[2]=(short)f2bf(a0c.z); av[3]=(short)f2bf(a0c.w);
    av[4]=(short)f2bf(a1c.x); av[5]=(short)f2bf(a1c.y); av[6]=(short)f2bf(a1c.z); av[7]=(short)f2bf(a1c.w);
    #pragma unroll
    for (int nt = 0; nt < NT; ++nt)
      acc[nt] = __builtin_amdgcn_mfma_f32_16x16x32_bf16(av, bc[nt], acc[nt], 0, 0, 0);
    a0c = a0n; a1c = a1n;
    #pragma unroll
    for (int nt = 0; nt < NT; ++nt) bc[nt] = bn[nt];
  }
  if (quad == 0) {
    #pragma unroll
    for (int nt = 0; nt < NT; ++nt)
      #pragma unroll
      for (int r = 0; r < QB; ++r)
        red[w][r*CT + nt*16 + m] = acc[nt][r];
  }
  __syncthreads();
  // epilogue: QB * (CT/2) threads
  if (t < QB * (CT/2)) {
    const int o = t % (CT/2), ql = t / (CT/2);
    const int q = q0 + ql;
    float x = 0.0f, y = 0.0f;
    #pragma unroll
    for (int w2 = 0; w2 < NW; ++w2) {
      x += red[w2][ql*CT + o*2];
      y += red[w2][ql*CT + o*2 + 1];
    }
    const float* f = feats + (size_t)q * C2;
    for (int i = 0; i < I; ++i) {
      float fx = f[i*2], fy = f[i*2+1];
      float Av = Ad[o*I + i], Bv = Bd[o*I + i];
      x += Av*fx - Bv*fy;
      y += Av*fy + Bv*fx;
    }
    size_t idx = (size_t)q * (CT/2) + o;
    if (doRes) { x += prevOut[idx*2]; y += prevOut[idx*2+1]; }
    outCur[idx*2]   = x;
    outCur[idx*2+1] = y;
    float mm = x*x + y*y + 1e-6f;
    float sc = fmaxf(mm - 0.2f, 0.0f) / mm;
    inNext[idx*2]   = x * sc;
    inNext[idx*2+1] = y * sc;
  }
}

// ---------------------------------------------------------------- fused layer 4 (QB=4, 512 thr, split walks)
__global__ __launch_bounds__(512, 1) void fused_l4(
    const float* __restrict__ wl, const int* __restrict__ pl, const int* __restrict__ cnt,
    const float* __restrict__ in4, const float* __restrict__ K2C4,
    const float* __restrict__ Ad4, const float* __restrict__ Bd4,
    const float* __restrict__ p1, const float* __restrict__ p0,
    float* __restrict__ dout) {
  constexpr int QB = 4, Kd = 3072, KdP = 3136;
  __shared__ float Ml[QB * KdP];
  __shared__ float wsh[QB*512];
  __shared__ int   psh[QB*512];
  __shared__ int csh[QB];
  __shared__ float r4[QB][2][2];
  const int t = threadIdx.x;
  const int q0 = blockIdx.x * QB;
  for (int i = t; i < QB*KdP; i += 512) Ml[i] = 0.0f;
  if (t < QB) csh[t] = cnt[q0 + t];
  __syncthreads();
  stage_lists<QB, 512>(q0, csh, wl, pl, wsh, psh);
  __syncthreads();
  {
    const int ql = t / 128, rem = t % 128;
    const int half = rem / 64, c = rem % 64;
    const int q = q0 + ql;
    const int nnz = csh[ql];
    const int js = find_split(psh + ql*512, nnz);
    accum_range<64>(Ml + ql*KdP, (ql & 3) << 2, c, half ? js : 0, half ? nnz : js,
                    wsh + ql*512, psh + ql*512,
                    in4 + (size_t)(q >> 9)*512*64 + c);
  }
  __syncthreads();
  const int lane = t & 63, w = t >> 6;      // 8 waves
  const int ql = w >> 1, kh = w & 1;
  const int q = q0 + ql;
  const int sw = ql << 2;
  const float* Mq = Ml + ql*KdP;
  float a0 = 0.0f, a1 = 0.0f;
  for (int j = kh*1536 + lane; j < kh*1536 + 1536; j += 64) {
    float av = Mq[j ^ sw];
    a0 += av * K2C4[j*2];
    a1 += av * K2C4[j*2+1];
  }
  if (kh == 0 && lane < 32) {
    float fx = in4[q*64 + lane*2], fy = in4[q*64 + lane*2 + 1];
    float Av = Ad4[lane], Bv = Bd4[lane];
    a0 += Av*fx - Bv*fy;
    a1 += Av*fy + Bv*fx;
  }
  for (int off = 32; off > 0; off >>= 1) {
    a0 += __shfl_down(a0, off);
    a1 += __shfl_down(a1, off);
  }
  if (lane == 0) { r4[ql][kh][0] = a0; r4[ql][kh][1] = a1; }
  __syncthreads();
  if (t < QB) {
    int qq = q0 + t;
    float s0 = r4[t][0][0] + r4[t][1][0];
    float s1 = r4[t][0][1] + r4[t][1][1];
    float px = p1[qq*2]   + s0/128.0f;
    float py = p1[qq*2+1] + s1/128.0f;
    dout[qq*2] = px; dout[qq*2+1] = py;
    dout[4096 + qq*2]   = (px - p0[qq*2]) / 0.1f;
    dout[4096 + qq*2+1] = (py - p0[qq*2+1]) / 0.1f;
  }
}

// ---------------------------------------------------------------- launch
extern "C" void kernel_launch(void* const* d_in, const int* in_sizes, int n_in,
                              void* d_out, int out_size, void* d_ws, size_t ws_size,
                              hipStream_t stream) {
  (void)in_sizes; (void)n_in; (void)out_size; (void)ws_size;
  const float* v0_enc = (const float*)d_in[1];
  const float* p0     = (const float*)d_in[2];
  const float* v0     = (const float*)d_in[3];
  const float* a      = (const float*)d_in[4];
  const float* other  = (const float*)d_in[5];
  const float* box    = (const float*)d_in[6];
  const float* boxf   = (const float*)d_in[7];
  const float* fmask  = (const float*)d_in[8];
  const float* bmask  = (const float*)d_in[9];
  const float* Wcf = (const float*)d_in[10];
  const float* Wco = (const float*)d_in[11];
  const float* Adf = (const float*)d_in[12];
  const float* Bdf = (const float*)d_in[13];
  const float* Wc1 = (const float*)d_in[14];
  const float* Ad1 = (const float*)d_in[15];
  const float* Bd1 = (const float*)d_in[16];
  const float* Wc2 = (const float*)d_in[17];
  const float* Ad2 = (const float*)d_in[18];
  const float* Bd2 = (const float*)d_in[19];
  const float* Wc3 = (const float*)d_in[20];
  const float* Ad3 = (const float*)d_in[21];
  const float* Bd3 = (const float*)d_in[22];
  const float* Wc4 = (const float*)d_in[23];
  const float* Ad4 = (const float*)d_in[24];
  const float* Bd4 = (const float*)d_in[25];

  float* ws = (float*)d_ws;
  float* P1    = ws + 0;          // 4096
  float* F0    = ws + 4096;       // 98304  (stride 48, padded)
  unsigned short* K2CF = (unsigned short*)(ws + 102400);  // [32][2304] bf16 T
  float* K2CO  = ws + 176128;     // [96][32] fp32
  unsigned short* K2C1 = (unsigned short*)(ws + 179200);  // [64][4608] bf16 T
  unsigned short* K2C2 = (unsigned short*)(ws + 474112);  // [64][3072] bf16 T
  unsigned short* K2C3 = (unsigned short*)(ws + 670720);
  float* K2C4  = ws + 867328;     // [3072][2] fp32
  float* WFl   = ws + 873472;     // 1048576
  int*   PFl   = (int*)(ws + 1922048);   // 1048576
  int*   CNTF  = (int*)(ws + 2970624);   // 2048
  int*   CNTO  = (int*)(ws + 2972672);   // 2048
  float* IN1   = ws + 2974720;    // 196608 (2048 x 96)
  float* IN2   = ws + 3171328;    // 131072
  float* IN3   = ws + 3302400;    // 131072
  float* IN4   = ws + 3433472;    // 131072
  float* OUTA  = ws + 3564544;    // 131072
  float* OUTB  = ws + 3695616;    // 131072
  float* GPART = ws + 4027392;    // 16 x 2048 x 64 fp32 (L1 k-split partials)
  unsigned short* MBUF = (unsigned short*)(ws + 6124544); // bf16 2048 x 4608
  float* WOl   = ws + 15561728;   // 1048576
  int*   POl   = (int*)(ws + 16610304);  // 1048576

  // 1: setup (P1/F0/steer tables)
  setup_kernel<<<761, 256, 0, stream>>>(p0, v0, a, other, v0_enc, P1, F0,
                                        Wcf, K2CF, Wco, K2CO, Wc1, K2C1,
                                        Wc2, K2C2, Wc3, K2C3, Wc4, K2C4);
  // 2: pair lists (stable bin-sorted)
  pairs_all<<<1024, 256, 0, stream>>>(P1, P1, fmask, WFl, PFl, CNTF,
                                      box, bmask, WOl, POl, CNTO);
  // 3: stage 0 fused -> IN1
  fused_s0<<<512, 512, 0, stream>>>(WFl, PFl, CNTF, F0, K2CF,
                                    WOl, POl, CNTO, boxf, K2CO, Adf, Bdf, IN1);
  // 4: layer 1 (I=48 -> O=32): accum -> MBUF, tiled MFMA GEMM, epilogue
  accum4<96, 2, 384><<<1024, 384, 0, stream>>>(WFl, PFl, CNTF, IN1, MBUF);
  gemm_mfma<64><<<dim3(64, 4), 256, 0, stream>>>(MBUF, K2C1, GPART, 4608, 288); // SPLIT=16
  epilogueL<<<256, 256, 0, stream>>>(GPART, 16, IN1, 48, Ad1, Bd1, nullptr, 0, OUTA, IN2);
  // 5: layer 2 (I=32 -> O=32, residual)
  fused_layer<64, 64, 32, 4><<<512, 512, 0, stream>>>(WFl, PFl, CNTF, IN2, K2C2,
                                                      Ad2, Bd2, OUTA, 1, OUTB, IN3);
  // 6: layer 3 (I=32 -> O=32, residual)
  fused_layer<64, 64, 32, 4><<<512, 512, 0, stream>>>(WFl, PFl, CNTF, IN3, K2C3,
                                                      Ad3, Bd3, OUTB, 1, OUTA, IN4);
  // 7: layer 4 fused thin GEMM + apply_correction
  fused_l4<<<512, 512, 0, stream>>>(WFl, PFl, CNTF, IN4, K2C4, Ad4, Bd4,
                                    P1, p0, (float*)d_out);
}

// Round 15
// 289.804 us; speedup vs baseline: 1.0168x; 1.0047x over previous
//
#include <hip/hip_runtime.h>
#include <cstdint>
#include <cstddef>

#define PI_F 3.14159265358979323846f

constexpr int BB = 4, NN = 512, BN = 2048, NBIN = 48;

typedef __attribute__((ext_vector_type(8))) short v8s;   // 8 bf16 (4 VGPRs)
typedef __attribute__((ext_vector_type(4))) float v4f;   // MFMA acc

__device__ __forceinline__ unsigned short f2bf(float f) {
  unsigned u = __float_as_uint(f);
  unsigned r = (u + 0x7FFFu + ((u >> 16) & 1u)) >> 16;   // RNE
  return (unsigned short)r;
}
__device__ __forceinline__ float bf2f(unsigned short s) {
  return __uint_as_float(((unsigned)s) << 16);
}

// ---------------------------------------------------------------- steer variants
__device__ __forceinline__ void steer_f32(const float* __restrict__ W, float* __restrict__ K2,
                                          int O, int I, int Ipad, int idx, int total) {
  if (idx >= total) return;
  int i = idx % Ipad;
  int o = (idx / Ipad) % O;
  int k = idx / (Ipad * O);
  int CTc = O * 2;
  size_t r0 = (size_t)((k*Ipad + i)*2 + 0) * CTc + o*2;
  size_t r1 = r0 + CTc;
  if (i >= I) { K2[r0]=0.f; K2[r0+1]=0.f; K2[r1]=0.f; K2[r1+1]=0.f; return; }
  int tt = k % 16;
  float ang = (tt + 0.5f) * (2.0f * PI_F / 16.0f) - PI_F;
  float ct = cosf(ang), st = sinf(ang);
  const float* Wp = W + ((size_t)(k*O + o)*I + i) * 4;
  float w00 = Wp[0], w01 = Wp[1], w10 = Wp[2], w11 = Wp[3];
  float rw00 = ct*w00 - st*w10, rw01 = ct*w01 - st*w11;
  float rw10 = st*w00 + ct*w10, rw11 = st*w01 + ct*w11;
  K2[r0 + 0] = rw00*ct - rw01*st;
  K2[r0 + 1] = rw10*ct - rw11*st;
  K2[r1 + 0] = rw00*st + rw01*ct;
  K2[r1 + 1] = rw10*st + rw11*ct;
}

__device__ __forceinline__ void steer_bf16T(const float* __restrict__ W,
                                            unsigned short* __restrict__ K2T,
                                            int O, int I, int Ipad, int Kd,
                                            int idx, int total) {
  if (idx >= total) return;
  int i = idx % Ipad;
  int o = (idx / Ipad) % O;
  int k = idx / (Ipad * O);
  size_t c0 = (size_t)(o*2 + 0) * Kd + (k*Ipad + i)*2;
  size_t c1 = (size_t)(o*2 + 1) * Kd + (k*Ipad + i)*2;
  if (i >= I) { K2T[c0]=0; K2T[c0+1]=0; K2T[c1]=0; K2T[c1+1]=0; return; }
  int tt = k % 16;
  float ang = (tt + 0.5f) * (2.0f * PI_F / 16.0f) - PI_F;
  float ct = cosf(ang), st = sinf(ang);
  const float* Wp = W + ((size_t)(k*O + o)*I + i) * 4;
  float w00 = Wp[0], w01 = Wp[1], w10 = Wp[2], w11 = Wp[3];
  float rw00 = ct*w00 - st*w10, rw01 = ct*w01 - st*w11;
  float rw10 = st*w00 + ct*w10, rw11 = st*w01 + ct*w11;
  K2T[c0 + 0] = f2bf(rw00*ct - rw01*st);
  K2T[c0 + 1] = f2bf(rw00*st + rw01*ct);
  K2T[c1 + 0] = f2bf(rw10*ct - rw11*st);
  K2T[c1 + 1] = f2bf(rw10*st + rw11*ct);
}

// ---------------------------------------------------------------- setup: prep + all steers
__global__ __launch_bounds__(256) void setup_kernel(
    const float* __restrict__ p0, const float* __restrict__ v0,
    const float* __restrict__ a, const float* __restrict__ other,
    const float* __restrict__ v0enc, float* __restrict__ p1, float* __restrict__ F0,
    const float* Wcf, unsigned short* K2CF, const float* Wco, float* K2CO,
    const float* Wc1, unsigned short* K2C1, const float* Wc2, unsigned short* K2C2,
    const float* Wc3, unsigned short* K2C3, const float* Wc4, float* K2C4) {
  int blk = blockIdx.x;
  int t = threadIdx.x;
  if (blk < 8) {
    int n = blk * 256 + t;
    float p0x = p0[n*2], p0y = p0[n*2+1];
    float v0x = v0[n*2], v0y = v0[n*2+1];
    float ax = a[n*2],  ay = a[n*2+1];
    float v1x = v0x + 0.1f*ax, v1y = v0y + 0.1f*ay;
    p1[n*2]   = p0x + 0.1f*(v0x+v1x)*0.5f;
    p1[n*2+1] = p0y + 0.1f*(v0y+v1y)*0.5f;
    float* F = F0 + (size_t)n*48;
    F[0] = v1x; F[1] = v1y;
    for (int c = 0; c < 3; ++c) {
      F[2+c*2]   = other[(n*3+c)*2];
      F[2+c*2+1] = other[(n*3+c)*2+1];
    }
    for (int c = 0; c < 16; ++c) {
      F[8+c*2]   = v0enc[(n*16+c)*2];
      F[8+c*2+1] = v0enc[(n*16+c)*2+1];
    }
    for (int c = 40; c < 48; ++c) F[c] = 0.0f;
  } else if (blk < 80)  steer_bf16T(Wcf, K2CF, 16, 20, 24, 2304, (blk-8)*256 + t, 18432);
  else if (blk < 83)  steer_f32(Wco, K2CO, 16, 1, 1,   (blk-80)*256 + t, 768);
  else if (blk < 371) steer_bf16T(Wc1, K2C1, 32, 48, 48, 4608, (blk-83)*256 + t, 73728);
  else if (blk < 563) steer_bf16T(Wc2, K2C2, 32, 32, 32, 3072, (blk-371)*256 + t, 49152);
  else if (blk < 755) steer_bf16T(Wc3, K2C3, 32, 32, 32, 3072, (blk-563)*256 + t, 49152);
  else                steer_f32(Wc4, K2C4, 1, 32, 32,  (blk-755)*256 + t, 1536);
}

// ---------------------------------------------------------------- pairs + stable bin-sorted compaction (R9-proven)
__global__ __launch_bounds__(256) void pairs_all(const float* __restrict__ qry,
                                                 const float* __restrict__ srcF,
                                                 const float* __restrict__ maskF,
                                                 float* __restrict__ wlF, int* __restrict__ plF,
                                                 int* __restrict__ cntF,
                                                 const float* __restrict__ srcO,
                                                 const float* __restrict__ maskO,
                                                 float* __restrict__ wlO, int* __restrict__ plO,
                                                 int* __restrict__ cntO) {
  __shared__ int hist[4][48];
  __shared__ int bstart[4][48];
  __shared__ int runc[4][48];
  bool isBox = blockIdx.x >= 512;
  int qblk = isBox ? (blockIdx.x - 512) : blockIdx.x;
  const float* src = isBox ? srcO : srcF;
  const float* mask = isBox ? maskO : maskF;
  float* wlist = isBox ? wlO : wlF;
  int* plist = isBox ? plO : plF;
  int* cnt = isBox ? cntO : cntF;

  int wv = threadIdx.x >> 6;
  int lane = threadIdx.x & 63;
  int q = qblk * 4 + wv;
  int b = q >> 9;
  float qx = qry[q*2], qy = qry[q*2+1];
  const float* sb = src + b*1024;
  const float* mb = mask + (size_t)q*512;
  float* wl = wlist + (size_t)q*512;
  int* pl = plist + (size_t)q*512;

  if (lane < 48) { hist[wv][lane] = 0; runc[wv][lane] = 0; }

  float wreg[8]; int kreg[8];
  unsigned char predreg[8];
  for (int ch = 0; ch < 8; ++ch) {
    int s = ch*64 + lane;
    float sx = sb[s*2], sy = sb[s*2+1];
    float rx = sx - qx, ry = sy - qy;
    float d2 = rx*rx + ry*ry;
    float m = mb[s];
    float wi = fmaxf(1.0f - d2 / 1600.0f, 0.0f);
    float w = wi*wi*wi*m;
    bool pred = w > 0.0f;
    int k = 63;
    if (pred) {
      float dist = sqrtf(d2 + 1e-9f);
      float theta = atan2f(ry, rx);
      int rb = (int)(dist / 40.0f * 3.0f);
      rb = rb > 2 ? 2 : rb;
      float u = (theta + PI_F) / (2.0f * PI_F) * 16.0f;
      int tb = ((int)floorf(u)) & 15;
      k = rb*16 + tb;
      atomicAdd(&hist[wv][k], 1);
    }
    wreg[ch] = w; kreg[ch] = k; predreg[ch] = pred ? 1 : 0;
  }
  int cntv = (lane < 48) ? hist[wv][lane] : 0;
  int sc = cntv;
  #pragma unroll
  for (int off = 1; off < 64; off <<= 1) {
    int o = __shfl_up(sc, off);
    if (lane >= off) sc += o;
  }
  if (lane < 48) bstart[wv][lane] = sc - cntv;
  if (lane == 47) cnt[q] = sc;

  for (int ch = 0; ch < 8; ++ch) {
    bool pred = predreg[ch] != 0;
    int k = kreg[ch];
    float w = wreg[ch];
    unsigned long long mEq = __ballot(pred);
    #pragma unroll
    for (int bit = 0; bit < 6; ++bit) {
      unsigned long long mbm = __ballot((k >> bit) & 1);
      mEq &= ((k >> bit) & 1) ? mbm : ~mbm;
    }
    int rank = __popcll(mEq & ((1ull<<lane)-1ull));
    int total = __popcll(mEq);
    if (pred) {
      int bs = bstart[wv][k];
      int rc = runc[wv][k];
      int pos = bs + rc + rank;
      int s = ch*64 + lane;
      wl[pos] = w;
      pl[pos] = (s<<6) | k;
      if (rank == total - 1) runc[wv][k] = rc + total;
    }
  }
}

// ---------------------------------------------------------------- split point: end of run containing median (R10-proven)
__device__ __forceinline__ int find_split(const int* __restrict__ pls, int nnz) {
  if (nnz <= 0) return 0;
  int kmid = pls[nnz >> 1] & 63;
  int lo = nnz >> 1, hi = nnz;
  while (lo < hi) {
    int m2 = (lo + hi) >> 1;
    if ((pls[m2] & 63) > kmid) hi = m2; else lo = m2 + 1;
  }
  return lo;   // first j with bin > kmid
}

// ---------------------------------------------------------------- run-based accum over [jbeg, jend) (R10-proven scalar)
// Sorted lists -> register run accumulation, write-only LDS. Padding writes go to
// dummy bin 48 (slab stride (NBIN+1)*C2). Per-bin add order = s order (stable sort,
// runs not split across halves) -> bit-identical sums.
template<int C2>
__device__ __forceinline__ void accum_range(float* __restrict__ M, int sw, int c,
    int jbeg, int jend,
    const float* __restrict__ wls, const int* __restrict__ pls,
    const float* __restrict__ fb) {
  int len = jend - jbeg;
  if (len <= 0) return;
  const float* wp = wls + jbeg;
  const int* pp = pls + jbeg;
  constexpr int W = 16;
  float wA[W], fA[W]; int kA[W];
  #pragma unroll
  for (int j = 0; j < W; ++j) {
    bool v = j < len;
    float wv = v ? wp[j] : 0.0f;
    int p = v ? pp[j] : 0;
    wA[j] = wv; kA[j] = v ? (p & 63) : NBIN;
    fA[j] = fb[(p >> 6) * C2];
  }
  int kcur = -1;
  float acc = 0.0f;
  for (int base = 0; base < len; base += W) {
    float wB[W], fB[W]; int kB[W];
    if (base + W < len) {
      #pragma unroll
      for (int j = 0; j < W; ++j) {
        int idx = base + W + j;
        bool v = idx < len;
        float wv = v ? wp[idx] : 0.0f;
        int p = v ? pp[idx] : 0;
        wB[j] = wv; kB[j] = v ? (p & 63) : NBIN;
        fB[j] = fb[(size_t)(p >> 6) * C2];
      }
    }
    asm volatile("" ::: "memory");   // keep next-window loads issued before stores
    #pragma unroll
    for (int j = 0; j < W; ++j) {
      acc = (kA[j] == kcur ? acc : 0.0f) + wA[j] * fA[j];
      kcur = kA[j];
      M[(kcur * C2 + c) ^ sw] = acc;
    }
    #pragma unroll
    for (int j = 0; j < W; ++j) { wA[j] = wB[j]; kA[j] = kB[j]; fA[j] = fB[j]; }
  }
}

// ---------------------------------------------------------------- list staging helper
template<int QB, int TPB>
__device__ __forceinline__ void stage_lists(int q0, const int* __restrict__ csh,
    const float* __restrict__ wlist, const int* __restrict__ plist,
    float* __restrict__ wsh, int* __restrict__ psh) {
  const int t = threadIdx.x;
  for (int i = t; i < QB*128; i += TPB) {
    int qs = i >> 7, j = i & 127;
    if (j*4 < csh[qs]) {
      ((float4*)(wsh + qs*512))[j] = ((const float4*)(wlist + (size_t)(q0+qs)*512))[j];
      ((int4*)(psh + qs*512))[j]   = ((const int4*)(plist + (size_t)(q0+qs)*512))[j];
    }
  }
}

// ---------------------------------------------------------------- standalone accum -> bf16 MBUF (layer 1)
// QB=2 queries/block; per query: 2 walk-halves x C2 threads (1 channel each).
// launch_bounds (TPB, 4): LDS caps at 3 blocks/CU (~4.5 waves/SIMD); cap VGPR at 128
// so the W=16 gather window stays in registers.
template<int C2, int QB, int TPB>
__global__ __launch_bounds__(TPB, 4) void accum4(const float* __restrict__ wlist,
                                                 const int* __restrict__ plist,
                                                 const int* __restrict__ cnt,
                                                 const float* __restrict__ feats,
                                                 unsigned short* __restrict__ Mout) {
  constexpr int Kd = NBIN * C2;
  constexpr int KdP = Kd + C2;          // + dummy bin-48 row
  static_assert(TPB == 2 * QB * C2, "TPB must equal 2*QB*C2");
  __shared__ float Ml[QB * KdP];
  __shared__ float wsh[QB*512];
  __shared__ int   psh[QB*512];
  __shared__ int   csh[QB];
  const int t = threadIdx.x;
  const int q0 = blockIdx.x * QB;
  for (int i = t; i < QB*KdP; i += TPB) Ml[i] = 0.0f;
  if (t < QB) csh[t] = (q0 + t < BN) ? cnt[q0 + t] : 0;
  __syncthreads();
  stage_lists<QB, TPB>(q0, csh, wlist, plist, wsh, psh);
  __syncthreads();
  {
    const int ql = t / (2*C2);
    const int rem = t % (2*C2);
    const int half = rem / C2, c = rem % C2;
    const int q = q0 + ql;
    const int nnz = csh[ql];
    const int js = find_split(psh + ql*512, nnz);
    accum_range<C2>(Ml + ql*KdP, 0, c, half ? js : 0, half ? nnz : js,
                    wsh + ql*512, psh + ql*512,
                    feats + (size_t)(q >> 9)*512*C2 + c);
  }
  __syncthreads();
  for (int i = t; i < QB*(Kd/2); i += TPB) {
    int ql = i / (Kd/2), off = i % (Kd/2);
    float2 v = ((const float2*)(Ml + ql*KdP))[off];
    ((unsigned*)(Mout + (size_t)(q0+ql)*Kd))[off] =
        (unsigned)f2bf(v.x) | ((unsigned)f2bf(v.y) << 16);
  }
}

// ---------------------------------------------------------------- bf16 MFMA GEMM with k-split (R0-proven)
template<int CT>
__global__ __launch_bounds__(256) void gemm_mfma(const unsigned short* __restrict__ A,
                                                 const unsigned short* __restrict__ B,
                                                 float* __restrict__ G, int Kd, int kn) {
  const int lane = threadIdx.x & 63;
  const int w = threadIdx.x >> 6;
  const int mblk = blockIdx.x;
  const int ks = blockIdx.y * 4 + w;
  const int k0 = ks * kn;
  const int m = lane & 15, quad = lane >> 4;
  constexpr int NT = CT / 16;
  const unsigned short* Ar0 = A + (size_t)(mblk*32 + m) * Kd + k0 + quad*8;
  const unsigned short* Ar1 = Ar0 + (size_t)16 * Kd;
  const unsigned short* Bp[NT];
  #pragma unroll
  for (int nt = 0; nt < NT; ++nt)
    Bp[nt] = B + (size_t)(nt*16 + m) * Kd + k0 + quad*8;
  v4f acc[2][NT];
  #pragma unroll
  for (int mt = 0; mt < 2; ++mt)
    for (int nt = 0; nt < NT; ++nt)
      acc[mt][nt] = (v4f){0.0f, 0.0f, 0.0f, 0.0f};
  for (int kt = 0; kt < kn; kt += 32) {
    v8s a0 = *(const v8s*)(Ar0 + kt);
    v8s a1 = *(const v8s*)(Ar1 + kt);
    #pragma unroll
    for (int nt = 0; nt < NT; ++nt) {
      v8s bv = *(const v8s*)(Bp[nt] + kt);
      acc[0][nt] = __builtin_amdgcn_mfma_f32_16x16x32_bf16(a0, bv, acc[0][nt], 0, 0, 0);
      acc[1][nt] = __builtin_amdgcn_mfma_f32_16x16x32_bf16(a1, bv, acc[1][nt], 0, 0, 0);
    }
  }
  float* Gb = G + ((size_t)ks * BN + mblk*32) * CT;
  #pragma unroll
  for (int mt = 0; mt < 2; ++mt)
    for (int nt = 0; nt < NT; ++nt)
      for (int r = 0; r < 4; ++r)
        Gb[(mt*16 + quad*4 + r) * CT + nt*16 + m] = acc[mt][nt][r];
}

// ---------------------------------------------------------------- layer epilogue w/ partials (R0-proven)
__global__ void epilogueL(const float* __restrict__ Gp, int SPLIT,
                          const float* __restrict__ inPrev, int I,
                          const float* __restrict__ Ad, const float* __restrict__ Bd,
                          const float* __restrict__ prevOut, int doRes,
                          float* __restrict__ outCur, float* __restrict__ inNext) {
  int idx = blockIdx.x * blockDim.x + threadIdx.x;
  if (idx >= BN*32) return;
  int o = idx % 32, q = idx / 32;
  float x = 0.0f, y = 0.0f;
  for (int sp = 0; sp < SPLIT; ++sp) {
    size_t base = ((size_t)sp*BN + q)*64 + o*2;
    x += Gp[base]; y += Gp[base+1];
  }
  const float* f = inPrev + (size_t)q * I * 2;
  for (int i = 0; i < I; ++i) {
    float fx = f[i*2], fy = f[i*2+1];
    float Av = Ad[o*I+i], Bv = Bd[o*I+i];
    x += Av*fx - Bv*fy;
    y += Av*fy + Bv*fx;
  }
  if (doRes) {
    x += prevOut[(size_t)idx*2];
    y += prevOut[(size_t)idx*2+1];
  }
  outCur[(size_t)idx*2]   = x;
  outCur[(size_t)idx*2+1] = y;
  float m = x*x + y*y + 1e-6f;
  float sc = fmaxf(m - 0.2f, 0.0f) / m;
  inNext[(size_t)idx*2]   = x * sc;
  inNext[(size_t)idx*2+1] = y * sc;
}

// ---------------------------------------------------------------- fused stage-0 (QB=4, 512 thr, split walks)
// launch_bounds (512,4): LDS caps at 2 blocks/CU (= 4 waves/SIMD); cap VGPR at 128.
__global__ __launch_bounds__(512, 4) void fused_s0(
    const float* __restrict__ wlF, const int* __restrict__ plF, const int* __restrict__ cntF,
    const float* __restrict__ F0, const unsigned short* __restrict__ K2CF,
    const float* __restrict__ wlO, const int* __restrict__ plO, const int* __restrict__ cntO,
    const float* __restrict__ boxf, const float* __restrict__ K2CO,
    const float* __restrict__ Adf, const float* __restrict__ Bdf,
    float* __restrict__ in1) {
  constexpr int QB = 4;
  constexpr int Kd = 2304;      // 48 bins * C2=48
  constexpr int KdP = 2352;     // + dummy row
  constexpr int NWv = 8;
  constexpr int KW = Kd / NWv;  // 288
  __shared__ float Ml[QB * KdP];
  __shared__ float Mo[QB * 98];
  __shared__ float red[NWv][QB * 32];
  __shared__ float wshF[QB*512];
  __shared__ int   pshF[QB*512];
  __shared__ float wshO[QB*512];
  __shared__ int   pshO[QB*512];
  __shared__ int cshF[QB];
  __shared__ int cshO[QB];
  const int t = threadIdx.x;
  const int q0 = blockIdx.x * QB;
  for (int i = t; i < QB*KdP; i += 512) Ml[i] = 0.0f;
  for (int i = t; i < QB*98; i += 512) Mo[i] = 0.0f;
  if (t < QB) cshF[t] = cntF[q0 + t];
  else if (t < 2*QB) cshO[t-QB] = cntO[q0 + t - QB];
  __syncthreads();
  for (int i = t; i < 2*QB*128; i += 512) {
    int half = i >> 9;
    int qs = (i >> 7) & (QB-1), j = i & 127;
    if (half == 0) {
      if (j*4 < cshF[qs]) {
        ((float4*)(wshF + qs*512))[j] = ((const float4*)(wlF + (size_t)(q0+qs)*512))[j];
        ((int4*)(pshF + qs*512))[j]   = ((const int4*)(plF + (size_t)(q0+qs)*512))[j];
      }
    } else {
      if (j*4 < cshO[qs]) {
        ((float4*)(wshO + qs*512))[j] = ((const float4*)(wlO + (size_t)(q0+qs)*512))[j];
        ((int4*)(pshO + qs*512))[j]   = ((const int4*)(plO + (size_t)(q0+qs)*512))[j];
      }
    }
  }
  __syncthreads();
  if (t < 384) {                      // fluid: 4 q x 2 halves x 48 ch
    const int ql = t / 96, rem = t % 96;
    const int half = rem / 48, c = rem % 48;
    const int q = q0 + ql;
    const int nnz = cshF[ql];
    const int js = find_split(pshF + ql*512, nnz);
    accum_range<48>(Ml + ql*KdP, ql << 2, c, half ? js : 0, half ? nnz : js,
                    wshF + ql*512, pshF + ql*512,
                    F0 + (size_t)(q >> 9)*512*48 + c);
  } else if (t < 400) {               // box: 4 q x 2 halves x 2 ch
    const int idx = t - 384;
    const int ql = idx >> 2, half = (idx >> 1) & 1, c = idx & 1;
    const int q = q0 + ql;
    const int nnz = cshO[ql];
    const int js = find_split(pshO + ql*512, nnz);
    accum_range<2>(Mo + ql*98, 0, c, half ? js : 0, half ? nnz : js,
                   wshO + ql*512, pshO + ql*512,
                   boxf + (size_t)(q >> 9)*1024 + c);
  }
  __syncthreads();
  // fluid GEMM: 8 waves k-split, CT=32 (NT=2), A rows duplicated mod 4; A/B prefetched
  {
    const int lane = t & 63, w = t >> 6;
    const int m = lane & 15, quad = lane >> 4;
    const int ar = m & 3;
    const int sw = ar << 2;
    const float* Abase = Ml + ar * KdP;
    const int kb = w * KW + quad * 8;
    const unsigned short* Bb0 = K2CF + (size_t)m * Kd + kb;
    const unsigned short* Bb1 = K2CF + (size_t)(16 + m) * Kd + kb;
    v4f acc[2];
    acc[0] = (v4f){0,0,0,0}; acc[1] = (v4f){0,0,0,0};
    float4 a0c = *(const float4*)(Abase + (kb ^ sw));
    float4 a1c = *(const float4*)(Abase + ((kb + 4) ^ sw));
    v8s b0c = *(const v8s*)(Bb0);
    v8s b1c = *(const v8s*)(Bb1);
    for (int kt = 0; kt < KW; kt += 32) {
      float4 a0n, a1n; v8s b0n, b1n;
      if (kt + 32 < KW) {
        const int jn = kb + kt + 32;
        a0n = *(const float4*)(Abase + (jn ^ sw));
        a1n = *(const float4*)(Abase + ((jn + 4) ^ sw));
        b0n = *(const v8s*)(Bb0 + kt + 32);
        b1n = *(const v8s*)(Bb1 + kt + 32);
      }
      v8s av;
      av[0]=(short)f2bf(a0c.x); av[1]=(short)f2bf(a0c.y); av[2]=(short)f2bf(a0c.z); av[3]=(short)f2bf(a0c.w);
      av[4]=(short)f2bf(a1c.x); av[5]=(short)f2bf(a1c.y); av[6]=(short)f2bf(a1c.z); av[7]=(short)f2bf(a1c.w);
      acc[0] = __builtin_amdgcn_mfma_f32_16x16x32_bf16(av, b0c, acc[0], 0, 0, 0);
      acc[1] = __builtin_amdgcn_mfma_f32_16x16x32_bf16(av, b1c, acc[1], 0, 0, 0);
      a0c = a0n; a1c = a1n; b0c = b0n; b1c = b1n;
    }
    if (quad == 0) {
      #pragma unroll
      for (int nt = 0; nt < 2; ++nt)
        #pragma unroll
        for (int r = 0; r < 4; ++r)
          red[w][r*32 + nt*16 + m] = acc[nt][r];
    }
  }
  __syncthreads();
  // epilogue0: 4 q x 48 ch
  if (t < 192) {
    const int ql = t / 48, ch = t % 48;
    const int q = q0 + ql;
    float x = 0.0f, y = 0.0f;
    if (ch < 16) {
      const float* Mq = Mo + ql*98;
      for (int j = 0; j < 96; ++j) {
        float mv = Mq[j];
        x += mv * K2CO[j*32 + ch*2];
        y += mv * K2CO[j*32 + ch*2 + 1];
      }
    } else if (ch < 32) {
      int o = ch - 16;
      #pragma unroll
      for (int w2 = 0; w2 < NWv; ++w2) {
        x += red[w2][ql*32 + o*2];
        y += red[w2][ql*32 + o*2 + 1];
      }
    } else {
      int o = ch - 32;
      const float* f = F0 + (size_t)q*48;
      for (int i = 0; i < 20; ++i) {
        float fx = f[i*2], fy = f[i*2+1];
        float Av = Adf[o*20+i], Bv = Bdf[o*20+i];
        x += Av*fx - Bv*fy;
        y += Av*fy + Bv*fx;
      }
    }
    float mm = x*x + y*y + 1e-6f;
    float sc = fmaxf(mm - 0.2f, 0.0f) / mm;
    size_t idx = (size_t)q*48 + ch;
    in1[idx*2]   = x * sc;
    in1[idx*2+1] = y * sc;
  }
}

// ---------------------------------------------------------------- fused layer (QB=4, 512 thr, split walks): layers 2-3
// launch_bounds (512,4): LDS caps at 2 blocks/CU (= 4 waves/SIMD); cap VGPR at 128.
template<int C2, int CT, int I, int QB>
__global__ __launch_bounds__(2*C2*QB, 4) void fused_layer(
    const float* __restrict__ wlist, const int* __restrict__ plist,
    const int* __restrict__ cnt, const float* __restrict__ feats,
    const unsigned short* __restrict__ K2T,
    const float* __restrict__ Ad, const float* __restrict__ Bd,
    const float* __restrict__ prevOut, int doRes,
    float* __restrict__ outCur, float* __restrict__ inNext) {
  constexpr int Kd = NBIN * C2;
  constexpr int KdP = Kd + C2;        // dummy row
  constexpr int TPB = 2 * C2 * QB;    // 512 for C2=64,QB=4
  constexpr int NW = TPB / 64;        // 8
  constexpr int KW = Kd / NW;         // 384
  constexpr int NT = CT / 16;
  static_assert(KW % 32 == 0, "KW must be multiple of 32");
  __shared__ float Ml[QB * KdP];
  __shared__ float red[NW][QB * CT];
  __shared__ float wsh[QB*512];
  __shared__ int   psh[QB*512];
  __shared__ int csh[QB];
  const int t = threadIdx.x;
  const int q0 = blockIdx.x * QB;
  for (int i = t; i < QB*KdP; i += TPB) Ml[i] = 0.0f;
  if (t < QB) csh[t] = cnt[q0 + t];
  __syncthreads();
  stage_lists<QB, TPB>(q0, csh, wlist, plist, wsh, psh);
  __syncthreads();
  {
    const int ql = t / (2*C2);
    const int rem = t % (2*C2);
    const int half = rem / C2, c = rem % C2;
    const int q = q0 + ql;
    const int nnz = csh[ql];
    const int js = find_split(psh + ql*512, nnz);
    accum_range<C2>(Ml + ql*KdP, (ql & 3) << 2, c, half ? js : 0, half ? nnz : js,
                    wsh + ql*512, psh + ql*512,
                    feats + (size_t)(q >> 9)*512*C2 + c);
  }
  __syncthreads();
  // GEMM: NW waves k-split; A rows duplicated mod QB; A/B prefetched one step ahead
  const int lane = t & 63, w = t >> 6;
  const int m = lane & 15, quad = lane >> 4;
  const int ar = m & (QB-1);
  const int sw = ar << 2;
  const float* Abase = Ml + ar * KdP;
  const int kb = w * KW + quad * 8;
  const unsigned short* Bb[NT];
  #pragma unroll
  for (int nt = 0; nt < NT; ++nt)
    Bb[nt] = K2T + (size_t)(nt*16 + m) * Kd + kb;
  v4f acc[NT];
  #pragma unroll
  for (int nt = 0; nt < NT; ++nt) acc[nt] = (v4f){0,0,0,0};
  float4 a0c = *(const float4*)(Abase + (kb ^ sw));
  float4 a1c = *(const float4*)(Abase + ((kb + 4) ^ sw));
  v8s bc[NT];
  #pragma unroll
  for (int nt = 0; nt < NT; ++nt) bc[nt] = *(const v8s*)(Bb[nt]);
  for (int kt = 0; kt < KW; kt += 32) {
    float4 a0n, a1n; v8s bn[NT];
    if (kt + 32 < KW) {
      const int jn = kb + kt + 32;
      a0n = *(const float4*)(Abase + (jn ^ sw));
      a1n = *(const float4*)(Abase + ((jn + 4) ^ sw));
      #pragma unroll
      for (int nt = 0; nt < NT; ++nt) bn[nt] = *(const v8s*)(Bb[nt] + kt + 32);
    }
    v8s av;
    av[0]=(short)f2bf(a0c.x); av[1]=(short)f2bf(a0c.y); av[2]=(short)f2bf(a0c.z); av[3]=(short)f2bf(a0c.w);
    av[4]=(short)f2bf(a1c.x); av[5]=(short)f2bf(a1c.y); av[6]=(short)f2bf(a1c.z); av[7]=(short)f2bf(a1c.w);
    #pragma unroll
    for (int nt = 0; nt < NT; ++nt)
      acc[nt] = __builtin_amdgcn_mfma_f32_16x16x32_bf16(av, bc[nt], acc[nt], 0, 0, 0);
    a0c = a0n; a1c = a1n;
    #pragma unroll
    for (int nt = 0; nt < NT; ++nt) bc[nt] = bn[nt];
  }
  if (quad == 0) {
    #pragma unroll
    for (int nt = 0; nt < NT; ++nt)
      #pragma unroll
      for (int r = 0; r < QB; ++r)
        red[w][r*CT + nt*16 + m] = acc[nt][r];
  }
  __syncthreads();
  // epilogue: QB * (CT/2) threads
  if (t < QB * (CT/2)) {
    const int o = t % (CT/2), ql = t / (CT/2);
    const int q = q0 + ql;
    float x = 0.0f, y = 0.0f;
    #pragma unroll
    for (int w2 = 0; w2 < NW; ++w2) {
      x += red[w2][ql*CT + o*2];
      y += red[w2][ql*CT + o*2 + 1];
    }
    const float* f = feats + (size_t)q * C2;
    for (int i = 0; i < I; ++i) {
      float fx = f[i*2], fy = f[i*2+1];
      float Av = Ad[o*I + i], Bv = Bd[o*I + i];
      x += Av*fx - Bv*fy;
      y += Av*fy + Bv*fx;
    }
    size_t idx = (size_t)q * (CT/2) + o;
    if (doRes) { x += prevOut[idx*2]; y += prevOut[idx*2+1]; }
    outCur[idx*2]   = x;
    outCur[idx*2+1] = y;
    float mm = x*x + y*y + 1e-6f;
    float sc = fmaxf(mm - 0.2f, 0.0f) / mm;
    inNext[idx*2]   = x * sc;
    inNext[idx*2+1] = y * sc;
  }
}

// ---------------------------------------------------------------- fused layer 4 (QB=4, 512 thr, split walks)
// launch_bounds (512,4): LDS caps at 2 blocks/CU; cap VGPR at 128.
__global__ __launch_bounds__(512, 4) void fused_l4(
    const float* __restrict__ wl, const int* __restrict__ pl, const int* __restrict__ cnt,
    const float* __restrict__ in4, const float* __restrict__ K2C4,
    const float* __restrict__ Ad4, const float* __restrict__ Bd4,
    const float* __restrict__ p1, const float* __restrict__ p0,
    float* __restrict__ dout) {
  constexpr int QB = 4, Kd = 3072, KdP = 3136;
  __shared__ float Ml[QB * KdP];
  __shared__ float wsh[QB*512];
  __shared__ int   psh[QB*512];
  __shared__ int csh[QB];
  __shared__ float r4[QB][2][2];
  const int t = threadIdx.x;
  const int q0 = blockIdx.x * QB;
  for (int i = t; i < QB*KdP; i += 512) Ml[i] = 0.0f;
  if (t < QB) csh[t] = cnt[q0 + t];
  __syncthreads();
  stage_lists<QB, 512>(q0, csh, wl, pl, wsh, psh);
  __syncthreads();
  {
    const int ql = t / 128, rem = t % 128;
    const int half = rem / 64, c = rem % 64;
    const int q = q0 + ql;
    const int nnz = csh[ql];
    const int js = find_split(psh + ql*512, nnz);
    accum_range<64>(Ml + ql*KdP, (ql & 3) << 2, c, half ? js : 0, half ? nnz : js,
                    wsh + ql*512, psh + ql*512,
                    in4 + (size_t)(q >> 9)*512*64 + c);
  }
  __syncthreads();
  const int lane = t & 63, w = t >> 6;      // 8 waves
  const int ql = w >> 1, kh = w & 1;
  const int q = q0 + ql;
  const int sw = ql << 2;
  const float* Mq = Ml + ql*KdP;
  float a0 = 0.0f, a1 = 0.0f;
  for (int j = kh*1536 + lane; j < kh*1536 + 1536; j += 64) {
    float av = Mq[j ^ sw];
    a0 += av * K2C4[j*2];
    a1 += av * K2C4[j*2+1];
  }
  if (kh == 0 && lane < 32) {
    float fx = in4[q*64 + lane*2], fy = in4[q*64 + lane*2 + 1];
    float Av = Ad4[lane], Bv = Bd4[lane];
    a0 += Av*fx - Bv*fy;
    a1 += Av*fy + Bv*fx;
  }
  for (int off = 32; off > 0; off >>= 1) {
    a0 += __shfl_down(a0, off);
    a1 += __shfl_down(a1, off);
  }
  if (lane == 0) { r4[ql][kh][0] = a0; r4[ql][kh][1] = a1; }
  __syncthreads();
  if (t < QB) {
    int qq = q0 + t;
    float s0 = r4[t][0][0] + r4[t][1][0];
    float s1 = r4[t][0][1] + r4[t][1][1];
    float px = p1[qq*2]   + s0/128.0f;
    float py = p1[qq*2+1] + s1/128.0f;
    dout[qq*2] = px; dout[qq*2+1] = py;
    dout[4096 + qq*2]   = (px - p0[qq*2]) / 0.1f;
    dout[4096 + qq*2+1] = (py - p0[qq*2+1]) / 0.1f;
  }
}

// ---------------------------------------------------------------- launch
extern "C" void kernel_launch(void* const* d_in, const int* in_sizes, int n_in,
                              void* d_out, int out_size, void* d_ws, size_t ws_size,
                              hipStream_t stream) {
  (void)in_sizes; (void)n_in; (void)out_size; (void)ws_size;
  const float* v0_enc = (const float*)d_in[1];
  const float* p0     = (const float*)d_in[2];
  const float* v0     = (const float*)d_in[3];
  const float* a      = (const float*)d_in[4];
  const float* other  = (const float*)d_in[5];
  const float* box    = (const float*)d_in[6];
  const float* boxf   = (const float*)d_in[7];
  const float* fmask  = (const float*)d_in[8];
  const float* bmask  = (const float*)d_in[9];
  const float* Wcf = (const float*)d_in[10];
  const float* Wco = (const float*)d_in[11];
  const float* Adf = (const float*)d_in[12];
  const float* Bdf = (const float*)d_in[13];
  const float* Wc1 = (const float*)d_in[14];
  const float* Ad1 = (const float*)d_in[15];
  const float* Bd1 = (const float*)d_in[16];
  const float* Wc2 = (const float*)d_in[17];
  const float* Ad2 = (const float*)d_in[18];
  const float* Bd2 = (const float*)d_in[19];
  const float* Wc3 = (const float*)d_in[20];
  const float* Ad3 = (const float*)d_in[21];
  const float* Bd3 = (const float*)d_in[22];
  const float* Wc4 = (const float*)d_in[23];
  const float* Ad4 = (const float*)d_in[24];
  const float* Bd4 = (const float*)d_in[25];

  float* ws = (float*)d_ws;
  float* P1    = ws + 0;          // 4096
  float* F0    = ws + 4096;       // 98304  (stride 48, padded)
  unsigned short* K2CF = (unsigned short*)(ws + 102400);  // [32][2304] bf16 T
  float* K2CO  = ws + 176128;     // [96][32] fp32
  unsigned short* K2C1 = (unsigned short*)(ws + 179200);  // [64][4608] bf16 T
  unsigned short* K2C2 = (unsigned short*)(ws + 474112);  // [64][3072] bf16 T
  unsigned short* K2C3 = (unsigned short*)(ws + 670720);
  float* K2C4  = ws + 867328;     // [3072][2] fp32
  float* WFl   = ws + 873472;     // 1048576
  int*   PFl   = (int*)(ws + 1922048);   // 1048576
  int*   CNTF  = (int*)(ws + 2970624);   // 2048
  int*   CNTO  = (int*)(ws + 2972672);   // 2048
  float* IN1   = ws + 2974720;    // 196608 (2048 x 96)
  float* IN2   = ws + 3171328;    // 131072
  float* IN3   = ws + 3302400;    // 131072
  float* IN4   = ws + 3433472;    // 131072
  float* OUTA  = ws + 3564544;    // 131072
  float* OUTB  = ws + 3695616;    // 131072
  float* GPART = ws + 4027392;    // 16 x 2048 x 64 fp32 (L1 k-split partials)
  unsigned short* MBUF = (unsigned short*)(ws + 6124544); // bf16 2048 x 4608
  float* WOl   = ws + 15561728;   // 1048576
  int*   POl   = (int*)(ws + 16610304);  // 1048576

  // 1: setup (P1/F0/steer tables)
  setup_kernel<<<761, 256, 0, stream>>>(p0, v0, a, other, v0_enc, P1, F0,
                                        Wcf, K2CF, Wco, K2CO, Wc1, K2C1,
                                        Wc2, K2C2, Wc3, K2C3, Wc4, K2C4);
  // 2: pair lists (stable bin-sorted)
  pairs_all<<<1024, 256, 0, stream>>>(P1, P1, fmask, WFl, PFl, CNTF,
                                      box, bmask, WOl, POl, CNTO);
  // 3: stage 0 fused -> IN1
  fused_s0<<<512, 512, 0, stream>>>(WFl, PFl, CNTF, F0, K2CF,
                                    WOl, POl, CNTO, boxf, K2CO, Adf, Bdf, IN1);
  // 4: layer 1 (I=48 -> O=32): accum -> MBUF, tiled MFMA GEMM, epilogue
  accum4<96, 2, 384><<<1024, 384, 0, stream>>>(WFl, PFl, CNTF, IN1, MBUF);
  gemm_mfma<64><<<dim3(64, 4), 256, 0, stream>>>(MBUF, K2C1, GPART, 4608, 288); // SPLIT=16
  epilogueL<<<256, 256, 0, stream>>>(GPART, 16, IN1, 48, Ad1, Bd1, nullptr, 0, OUTA, IN2);
  // 5: layer 2 (I=32 -> O=32, residual)
  fused_layer<64, 64, 32, 4><<<512, 512, 0, stream>>>(WFl, PFl, CNTF, IN2, K2C2,
                                                      Ad2, Bd2, OUTA, 1, OUTB, IN3);
  // 6: layer 3 (I=32 -> O=32, residual)
  fused_layer<64, 64, 32, 4><<<512, 512, 0, stream>>>(WFl, PFl, CNTF, IN3, K2C3,
                                                      Ad3, Bd3, OUTB, 1, OUTA, IN4);
  // 7: layer 4 fused thin GEMM + apply_correction
  fused_l4<<<512, 512, 0, stream>>>(WFl, PFl, CNTF, IN4, K2C4, Ad4, Bd4,
                                    P1, p0, (float*)d_out);
}